// Round 14
// baseline (2216.568 us; speedup 1.0000x reference)
//
#include <hip/hip_runtime.h>
#include <hip/hip_bf16.h>

typedef __bf16 bf16x8 __attribute__((ext_vector_type(8)));
typedef float f32x4 __attribute__((ext_vector_type(4)));
typedef float f32x4u __attribute__((ext_vector_type(4), aligned(4)));

#define NH 12
#define HD 64
#define SEQ 145
#define SP 160
#define DMODEL 768
#define NTOT 2304
#define BDIM 1024
#define RBS 148   // rbias padded row stride (4-aligned float4 rows)

// f32 -> bf16 RNE
__device__ __forceinline__ ushort f2bf(float f) {
  union { float f; uint u; } a; a.f = f;
  uint u = a.u;
  return (ushort)((u + 0x7FFFu + ((u >> 16) & 1u)) >> 16);
}

__device__ __forceinline__ int relidx(int qi, int ki) {
  if (ki == 0) return (qi == 0) ? 531 : 530;
  if (qi == 0) return 529;
  int q = qi - 1, k = ki - 1;
  int qh = q / 12, qw = q - qh * 12;
  int kh = k / 12, kw = k - kh * 12;
  return (qh - kh + 11) * 23 + (qw - kw + 11);
}

// async global->LDS, 16B per lane; lds dest = wave-uniform base + lane*16
__device__ __forceinline__ void gload_lds16(const ushort* g, ushort* l) {
  __builtin_amdgcn_global_load_lds(
      (const __attribute__((address_space(1))) void*)g,
      (__attribute__((address_space(3))) void*)l, 16, 0, 0);
}

#define VMCNT(n) do { asm volatile("s_waitcnt vmcnt(" #n ")" ::: "memory"); \
                      __builtin_amdgcn_sched_barrier(0); } while (0)

// ---------------- prep: Wt[n][k] = W_sel[k][n%768] as bf16 ----------------
__global__ void prep_w(const float* __restrict__ Wq, const float* __restrict__ Wk,
                       const float* __restrict__ Wv, ushort* __restrict__ Wt) {
  int i = blockIdx.x * 256 + threadIdx.x;
  if (i >= NTOT * DMODEL) return;
  int n = i / DMODEL, k = i - n * DMODEL;
  const float* W = (n < DMODEL) ? Wq : (n < 2 * DMODEL ? Wk : Wv);
  int c = n % DMODEL;
  Wt[i] = f2bf(W[k * DMODEL + c]);
}

// ---------------- x f32 -> bf16 (into d_out scratch) ----------------
__global__ void x2bf(const float* __restrict__ x, ushort* __restrict__ xb) {
  const size_t total = (size_t)BDIM * SEQ * DMODEL;
  size_t i = ((size_t)blockIdx.x * 256 + threadIdx.x) * 8;
  if (i >= total) return;
  float4 a = *reinterpret_cast<const float4*>(x + i);
  float4 c = *reinterpret_cast<const float4*>(x + i + 4);
  uint4 o;
  o.x = (uint)f2bf(a.x) | ((uint)f2bf(a.y) << 16);
  o.y = (uint)f2bf(a.z) | ((uint)f2bf(a.w) << 16);
  o.z = (uint)f2bf(c.x) | ((uint)f2bf(c.y) << 16);
  o.w = (uint)f2bf(c.z) | ((uint)f2bf(c.w) << 16);
  *reinterpret_cast<uint4*>(xb + i) = o;
}

// ---------------- zero pad region of transposed V buffer ----------------
__global__ void zero_vpad(ushort* __restrict__ vbuf) {
  int i = blockIdx.x * 256 + threadIdx.x;
  const int total = BDIM * NH * HD * (SP - SEQ);
  if (i >= total) return;
  int s = SEQ + i % (SP - SEQ);
  int row = i / (SP - SEQ);
  vbuf[(size_t)row * SP + s] = 0;
}

// ---------------- rel bias table: rbias[h][qi][ki], row stride RBS ----------------
__global__ void rel_prep(const float* __restrict__ tbl, float* __restrict__ rbias) {
  int i = blockIdx.x * 256 + threadIdx.x;
  if (i >= NH * SEQ * RBS) return;
  int h = i / (SEQ * RBS);
  int rem = i - h * SEQ * RBS;
  int qi = rem / RBS, ki = rem - qi * RBS;
  rbias[i] = (ki < SEQ) ? tbl[relidx(qi, ki) * NH + h] : 0.f;
}

// ---------------- fused QKV GEMM: [148480,768] x [768,2304] ----------------
// 128x256 tile, 8 waves (2x4), per-wave 64x64; BK=32 TRIPLE-buffered (72 KB
// LDS -> 2 blocks/CU). Stage t+2 while computing t, vmcnt(3). V-epilogue
// transposes through per-wave LDS so global stores are coalesced 16B.
#define GNT 9
#define GNWG 10440   // 1160 * 9
#define NKT 24       // 768 / 32

__global__ __launch_bounds__(512, 4)
void qkv_gemm(const ushort* __restrict__ xb, const ushort* __restrict__ Wt,
              const float* __restrict__ bq, const float* __restrict__ bv,
              ushort* __restrict__ qbuf, ushort* __restrict__ kbuf,
              ushort* __restrict__ vbuf) {
  // A[3][4096] at 0; B[3][8192] at 12288 (ushort indices). 72 KB total.
  // After the K-loop this array is reused as 8 x 4608-ushort per-wave
  // transpose scratch (8*9216 B = 73728 B, exact fit).
  __shared__ __align__(16) ushort lds[36864];

  int bid = blockIdx.x;
  int logical = (bid & 7) * 1305 + (bid >> 3);   // 10440 % 8 == 0, bijective
  int mt = logical / GNT, nt = logical - (logical / GNT) * GNT;
  int m0 = mt * 128, n0 = nt * 256;

  int tid = threadIdx.x;
  int l = tid & 63, w = tid >> 6;
  int wm = w >> 2, wn = w & 3;          // 2 x 4 wave grid
  int l15 = l & 15, l4 = l >> 4;
  int rslot = l4 ^ ((l15 >> 1) & 3);    // read-side swizzle (BK=32: 4 slots)

  // staging: thread t -> row (t>>2), stored slot (t&3); src chunk inverse-swz
  int srow = tid >> 2;                  // 0..127
  int schunk = (tid & 3) ^ ((tid >> 3) & 3);
  const ushort* aSrc  = xb + (size_t)(m0 + srow) * DMODEL + schunk * 8;
  const ushort* bSrc0 = Wt + (size_t)(n0 + srow) * DMODEL + schunk * 8;
  const ushort* bSrc1 = Wt + (size_t)(n0 + 128 + srow) * DMODEL + schunk * 8;
  int wdst = w << 9;   // w*512 ushorts (wave-contiguous dest)

#define STAGE(db, kof) do { \
    gload_lds16(aSrc  + (kof), &lds[(db) * 4096 + wdst]); \
    gload_lds16(bSrc0 + (kof), &lds[12288 + (db) * 8192 + wdst]); \
    gload_lds16(bSrc1 + (kof), &lds[12288 + (db) * 8192 + 4096 + wdst]); \
  } while (0)

  f32x4 acc[4][4];
  #pragma unroll
  for (int m = 0; m < 4; m++)
    #pragma unroll
    for (int n = 0; n < 4; n++)
      #pragma unroll
      for (int e = 0; e < 4; e++) acc[m][n][e] = 0.f;

  bf16x8 af[4], bfv[4];

#define LOADFRAG(db) do { \
    int ab_ = (db) * 4096, bb_ = 12288 + (db) * 8192; \
    _Pragma("unroll") \
    for (int i_ = 0; i_ < 4; i_++) \
      af[i_] = *reinterpret_cast<const bf16x8*>( \
          &lds[ab_ + ((wm * 64 + i_ * 16 + l15) << 5) + rslot * 8]); \
    _Pragma("unroll") \
    for (int n_ = 0; n_ < 4; n_++) \
      bfv[n_] = *reinterpret_cast<const bf16x8*>( \
          &lds[bb_ + ((wn * 64 + n_ * 16 + l15) << 5) + rslot * 8]); \
  } while (0)
#define MFMA16() do { \
    __builtin_amdgcn_s_setprio(1); \
    _Pragma("unroll") \
    for (int i_ = 0; i_ < 4; i_++) \
      _Pragma("unroll") \
      for (int n_ = 0; n_ < 4; n_++) \
        acc[i_][n_] = __builtin_amdgcn_mfma_f32_16x16x32_bf16( \
            af[i_], bfv[n_], acc[i_][n_], 0, 0, 0); \
    __builtin_amdgcn_s_setprio(0); \
  } while (0)

  // prologue: stage tiles 0 and 1; wait tile 0 only (tile 1 stays in flight)
  STAGE(0, 0);
  STAGE(1, 32);
  VMCNT(3);
  __builtin_amdgcn_s_barrier();

  #pragma unroll
  for (int t = 0; t < NKT; ++t) {
    int cur = t % 3, nx2 = (t + 2) % 3;
    if (t + 2 < NKT) STAGE(nx2, (t + 2) * 32);   // deep prefetch (tile t+2)
    LOADFRAG(cur);                                // published at t-1's barrier
    MFMA16();                                     // lgkmcnt auto-inserted
    if (t < NKT - 1) {
      if (t + 2 < NKT) { VMCNT(3); }              // retire t+1; t+2 in flight
      else             { VMCNT(0); }              // tail: retire final tile
      __builtin_amdgcn_s_barrier();               // publish t+1
    }
  }

  // ---- epilogue ----
  int which = n0 / DMODEL;
  int h_[4], dh_[4];
  float bias_[4];
  #pragma unroll
  for (int nn = 0; nn < 4; nn++) {
    int col = n0 + wn * 64 + nn * 16 + l15;
    int hcol = col - which * DMODEL;
    h_[nn] = hcol >> 6; dh_[nn] = hcol & 63;
    bias_[nn] = (which == 0) ? bq[hcol] : (which == 2 ? bv[hcol] : 0.f);
  }

  if (which != 2) {
    // q / k: coalesced-enough direct stores (dh consecutive per l15)
    #pragma unroll
    for (int i = 0; i < 4; i++) {
      #pragma unroll
      for (int r = 0; r < 4; r++) {
        int row = m0 + wm * 64 + i * 16 + (l4 << 2) + r;
        int b = row / SEQ;
        int s = row - b * SEQ;
        #pragma unroll
        for (int nn = 0; nn < 4; nn++) {
          float v = acc[i][nn][r] + bias_[nn];
          size_t bh = (size_t)b * NH + h_[nn];
          if (which == 0) {
            v *= 0.125f;  // fold 1/sqrt(64)
            qbuf[(bh * SEQ + s) * HD + dh_[nn]] = f2bf(v);
          } else {
            kbuf[(bh * SEQ + s) * HD + dh_[nn]] = f2bf(v);
          }
        }
      }
    }
  } else {
    // V: transpose through per-wave LDS, then coalesced 16B stores along s.
    __syncthreads();                 // all K-loop ds_reads complete; LDS free
    ushort* T = &lds[w * 4608];      // [64 cols(dh)][72 rows(s)+pad] per wave
    #pragma unroll
    for (int i = 0; i < 4; i++) {
      #pragma unroll
      for (int nn = 0; nn < 4; nn++) {
        int cl = nn * 16 + l15;          // col_local = dh index
        int rl = i * 16 + (l4 << 2);     // row_local base (4 rows)
        ushort4 pk;
        pk.x = f2bf(acc[i][nn][0] + bias_[nn]);
        pk.y = f2bf(acc[i][nn][1] + bias_[nn]);
        pk.z = f2bf(acc[i][nn][2] + bias_[nn]);
        pk.w = f2bf(acc[i][nn][3] + bias_[nn]);
        *reinterpret_cast<ushort4*>(&T[cl * 72 + rl]) = pk;   // ds_write_b64
      }
    }
    asm volatile("s_waitcnt lgkmcnt(0)" ::: "memory");
    __builtin_amdgcn_sched_barrier(0);
    int hU = ((n0 - 2 * DMODEL) >> 6) + wn;    // uniform head for this wave
    int rowbase = m0 + wm * 64;
    #pragma unroll
    for (int c = 0; c < 8; c++) {
      uint4 vv = *reinterpret_cast<const uint4*>(&T[l * 72 + c * 8]);
      int R = rowbase + c * 8;
      int b0 = R / SEQ;
      int b7 = (R + 7) / SEQ;
      if (b0 == b7) {
        int s0 = R - b0 * SEQ;
        size_t addr = (((size_t)b0 * NH + hU) * HD + l) * SP + s0;
        *reinterpret_cast<uint4*>(vbuf + addr) = vv;   // 16B contiguous in s
      } else {
        const ushort* pv = reinterpret_cast<const ushort*>(&vv);
        #pragma unroll
        for (int e = 0; e < 8; e++) {
          int row = R + e;
          int bb = row / SEQ, ss = row - bb * SEQ;
          vbuf[(((size_t)bb * NH + hU) * HD + l) * SP + ss] = pv[e];
        }
      }
    }
  }
#undef STAGE
#undef LOADFRAG
#undef MFMA16
}

// ---------------- fused windowed attention (swapped QK, no LDS sync) --------
// block = (b, strip, head-group of 4); 256 thr; NO barriers - mask read as
// coalesced float4 straight from L2 (b%8==xcd affinity). plds per-wave only.
// launch_bounds(256,7): VGPR cap 73 (compiler uses 64) -> 7 blocks/CU,
// 28 waves (87% occupancy) for TLP latency hiding.
#define AH 4
__global__ __launch_bounds__(256, 7)
void attn_kernel(const ushort* __restrict__ qbuf, const ushort* __restrict__ kbuf,
                 const ushort* __restrict__ vbuf, const float* __restrict__ mask,
                 const float* __restrict__ rbias, float* __restrict__ out) {
  __shared__ __align__(16) ushort plds[AH][16][SP + 8];  // 21 KB

  int id = blockIdx.x;
  int xcd = id & 7;
  int j = id >> 3;                 // 0..3839
  int b = xcd + 8 * (j / 30);      // b % 8 == xcd
  int rem = j % 30;
  int strip = rem / 3, hg = rem % 3;
  int r0 = strip * 16;

  int tid = threadIdx.x;
  int lane = tid & 63, w = tid >> 6;
  int h = hg * AH + w;             // wave -> head
  int l15 = lane & 15, l4 = lane >> 4;
  int bh = b * NH + h;

  int qi = r0 + l15;                       // this lane's query row
  int qc = (qi < SEQ) ? qi : (SEQ - 1);
  bool qok = (qi < SEQ);

  const ushort* qp = qbuf + (size_t)bh * SEQ * HD;
  const ushort* kp = kbuf + (size_t)bh * SEQ * HD;
  const ushort* vp = vbuf + (size_t)bh * HD * SP;
  const float* mrow = mask + (size_t)b * SEQ * SEQ + (size_t)qc * SEQ;
  const float* rp = rbias + (size_t)h * SEQ * RBS + (size_t)qc * RBS;

  // Q as the B-operand (col = qi)
  bf16x8 qf[2];
  if (qok) {
    qf[0] = *reinterpret_cast<const bf16x8*>(qp + qi * HD + l4 * 8);
    qf[1] = *reinterpret_cast<const bf16x8*>(qp + qi * HD + 32 + l4 * 8);
  } else {
    uint4 z = make_uint4(0, 0, 0, 0);
    qf[0] = *reinterpret_cast<bf16x8*>(&z);
    qf[1] = *reinterpret_cast<bf16x8*>(&z);
  }

  // scores: swapped mfma(K, Q) -> C[ki][qi]; lane holds 4 consecutive ki
  f32x4 sc[10];
  #pragma unroll
  for (int ct = 0; ct < 10; ct++)
    #pragma unroll
    for (int e = 0; e < 4; e++) sc[ct][e] = 0.f;
  #pragma unroll
  for (int ct = 0; ct < 10; ct++) {
    int krow = ct * 16 + l15;
    if (krow >= SEQ) krow = 0;   // clamp: real data, masked below
    bf16x8 kf0 = *reinterpret_cast<const bf16x8*>(kp + krow * HD + l4 * 8);
    bf16x8 kf1 = *reinterpret_cast<const bf16x8*>(kp + krow * HD + 32 + l4 * 8);
    sc[ct] = __builtin_amdgcn_mfma_f32_16x16x32_bf16(kf0, qf[0], sc[ct], 0, 0, 0);
    sc[ct] = __builtin_amdgcn_mfma_f32_16x16x32_bf16(kf1, qf[1], sc[ct], 0, 0, 0);
  }

  // mask + rel bias as float4 rows (ct 0..8 fully in-bounds: kb+3 <= 143)
  float mx = -3e38f;
  #pragma unroll
  for (int ct = 0; ct < 9; ct++) {
    int kb = ct * 16 + l4 * 4;
    f32x4u rb = *reinterpret_cast<const f32x4u*>(rp + kb);
    f32x4u mk = *reinterpret_cast<const f32x4u*>(mrow + kb);
    #pragma unroll
    for (int r = 0; r < 4; r++) {
      float v = sc[ct][r] + mk[r] + rb[r];
      float sv = qok ? v : -3e38f;
      sc[ct][r] = sv;
      mx = fmaxf(mx, sv);
    }
  }
  // ct 9: ki = 144 + l4*4 + r; only ki==144 (l4==0, r==0) is valid
  {
    float sv = -3e38f;
    if (l4 == 0 && qok) sv = sc[9][0] + mrow[144] + rp[144];
    sc[9][0] = sv;
    sc[9][1] = -3e38f; sc[9][2] = -3e38f; sc[9][3] = -3e38f;
    mx = fmaxf(mx, sv);
  }
  mx = fmaxf(mx, __shfl_xor(mx, 16, 64));
  mx = fmaxf(mx, __shfl_xor(mx, 32, 64));

  // exp + sum over ki
  float sum = 0.f;
  #pragma unroll
  for (int ct = 0; ct < 10; ct++)
    #pragma unroll
    for (int r = 0; r < 4; r++) {
      float p = __expf(sc[ct][r] - mx);
      sc[ct][r] = p;
      sum += p;
    }
  sum += __shfl_xor(sum, 16, 64);
  sum += __shfl_xor(sum, 32, 64);
  float inv = 1.f / sum;

  // P (bf16) to per-wave LDS: row = qi idx (l15), cols = ki; ushort4 stores
  #pragma unroll
  for (int ct = 0; ct < 10; ct++) {
    ushort4 pk;
    pk.x = f2bf(sc[ct][0] * inv);
    pk.y = f2bf(sc[ct][1] * inv);
    pk.z = f2bf(sc[ct][2] * inv);
    pk.w = f2bf(sc[ct][3] * inv);
    *reinterpret_cast<ushort4*>(&plds[w][l15][ct * 16 + l4 * 4]) = pk;
  }

  // PV: ctx[16 x 64]; V^T direct from global (pad cols zeroed)
  #pragma unroll
  for (int ntl = 0; ntl < 4; ntl++) {
    f32x4 pacc;
    #pragma unroll
    for (int e = 0; e < 4; e++) pacc[e] = 0.f;
    #pragma unroll
    for (int ks = 0; ks < 5; ks++) {
      bf16x8 pa = *reinterpret_cast<const bf16x8*>(
          &plds[w][l15][ks * 32 + l4 * 8]);
      bf16x8 vb = *reinterpret_cast<const bf16x8*>(
          vp + (ntl * 16 + l15) * SP + ks * 32 + l4 * 8);
      pacc = __builtin_amdgcn_mfma_f32_16x16x32_bf16(pa, vb, pacc, 0, 0, 0);
    }
    #pragma unroll
    for (int r = 0; r < 4; r++) {
      int s = r0 + l4 * 4 + r;
      if (s < SEQ)
        out[((size_t)b * SEQ + s) * DMODEL + h * HD + ntl * 16 + l15] = pacc[r];
    }
  }
}

extern "C" void kernel_launch(void* const* d_in, const int* in_sizes, int n_in,
                              void* d_out, int out_size, void* d_ws, size_t ws_size,
                              hipStream_t stream) {
  const float* x    = (const float*)d_in[0];
  const float* mask = (const float*)d_in[1];
  const float* Wq   = (const float*)d_in[2];
  const float* bq   = (const float*)d_in[3];
  const float* Wk   = (const float*)d_in[4];
  const float* Wv   = (const float*)d_in[5];
  const float* bv   = (const float*)d_in[6];
  const float* tbl  = (const float*)d_in[7];
  float* out = (float*)d_out;

  char* ws = (char*)d_ws;
  ushort* Wt = (ushort*)ws;                         // 3,538,944 B
  size_t off = (size_t)NTOT * DMODEL * 2;
  ushort* qbuf = (ushort*)(ws + off); off += (size_t)BDIM * NH * SEQ * HD * 2;
  ushort* kbuf = (ushort*)(ws + off); off += (size_t)BDIM * NH * SEQ * HD * 2;
  ushort* vbuf = (ushort*)(ws + off); off += (size_t)BDIM * NH * HD * SP * 2;
  float*  rbias = (float*)(ws + off); off += (size_t)NH * SEQ * RBS * 4 + 64;
  // ~713 MB of d_ws

  // bf16 x lives in d_out scratch (456 MB f32 out >= 228 MB bf16 x);
  // attn_kernel later overwrites every element of d_out.
  ushort* xbuf = (ushort*)d_out;

  prep_w<<<(NTOT * DMODEL + 255) / 256, 256, 0, stream>>>(Wq, Wk, Wv, Wt);
  zero_vpad<<<(BDIM * NH * HD * (SP - SEQ) + 255) / 256, 256, 0, stream>>>(vbuf);
  rel_prep<<<(NH * SEQ * RBS + 255) / 256, 256, 0, stream>>>(tbl, rbias);
  {
    size_t total = (size_t)BDIM * SEQ * DMODEL;
    x2bf<<<(int)(total / 8 / 256), 256, 0, stream>>>(x, xbuf);
  }

  qkv_gemm<<<GNWG, 512, 0, stream>>>(xbuf, Wt, bq, bv, qbuf, kbuf, vbuf);

  attn_kernel<<<BDIM * 10 * 3, 256, 0, stream>>>(qbuf, kbuf, vbuf, mask, rbias, out);
}

// Round 15
// 1506.402 us; speedup vs baseline: 1.4714x; 1.4714x over previous
//
#include <hip/hip_runtime.h>
#include <hip/hip_bf16.h>

typedef __bf16 bf16x8 __attribute__((ext_vector_type(8)));
typedef float f32x4 __attribute__((ext_vector_type(4)));
typedef float f32x4u __attribute__((ext_vector_type(4), aligned(4)));

#define NH 12
#define HD 64
#define SEQ 145
#define SP 160
#define DMODEL 768
#define NTOT 2304
#define BDIM 1024
#define RBS 148   // rbias padded row stride (4-aligned float4 rows)

// f32 -> bf16 RNE
__device__ __forceinline__ ushort f2bf(float f) {
  union { float f; uint u; } a; a.f = f;
  uint u = a.u;
  return (ushort)((u + 0x7FFFu + ((u >> 16) & 1u)) >> 16);
}

__device__ __forceinline__ int relidx(int qi, int ki) {
  if (ki == 0) return (qi == 0) ? 531 : 530;
  if (qi == 0) return 529;
  int q = qi - 1, k = ki - 1;
  int qh = q / 12, qw = q - qh * 12;
  int kh = k / 12, kw = k - kh * 12;
  return (qh - kh + 11) * 23 + (qw - kw + 11);
}

// async global->LDS, 16B per lane; lds dest = wave-uniform base + lane*16
__device__ __forceinline__ void gload_lds16(const ushort* g, ushort* l) {
  __builtin_amdgcn_global_load_lds(
      (const __attribute__((address_space(1))) void*)g,
      (__attribute__((address_space(3))) void*)l, 16, 0, 0);
}

#define VMCNT(n) do { asm volatile("s_waitcnt vmcnt(" #n ")" ::: "memory"); \
                      __builtin_amdgcn_sched_barrier(0); } while (0)

// ---------------- prep: Wt[n][k] = W_sel[k][n%768] as bf16 ----------------
__global__ void prep_w(const float* __restrict__ Wq, const float* __restrict__ Wk,
                       const float* __restrict__ Wv, ushort* __restrict__ Wt) {
  int i = blockIdx.x * 256 + threadIdx.x;
  if (i >= NTOT * DMODEL) return;
  int n = i / DMODEL, k = i - n * DMODEL;
  const float* W = (n < DMODEL) ? Wq : (n < 2 * DMODEL ? Wk : Wv);
  int c = n % DMODEL;
  Wt[i] = f2bf(W[k * DMODEL + c]);
}

// ---------------- x f32 -> bf16 (into d_out scratch) ----------------
__global__ void x2bf(const float* __restrict__ x, ushort* __restrict__ xb) {
  const size_t total = (size_t)BDIM * SEQ * DMODEL;
  size_t i = ((size_t)blockIdx.x * 256 + threadIdx.x) * 8;
  if (i >= total) return;
  float4 a = *reinterpret_cast<const float4*>(x + i);
  float4 c = *reinterpret_cast<const float4*>(x + i + 4);
  uint4 o;
  o.x = (uint)f2bf(a.x) | ((uint)f2bf(a.y) << 16);
  o.y = (uint)f2bf(a.z) | ((uint)f2bf(a.w) << 16);
  o.z = (uint)f2bf(c.x) | ((uint)f2bf(c.y) << 16);
  o.w = (uint)f2bf(c.z) | ((uint)f2bf(c.w) << 16);
  *reinterpret_cast<uint4*>(xb + i) = o;
}

// ---------------- zero pad region of transposed V buffer ----------------
__global__ void zero_vpad(ushort* __restrict__ vbuf) {
  int i = blockIdx.x * 256 + threadIdx.x;
  const int total = BDIM * NH * HD * (SP - SEQ);
  if (i >= total) return;
  int s = SEQ + i % (SP - SEQ);
  int row = i / (SP - SEQ);
  vbuf[(size_t)row * SP + s] = 0;
}

// ---------------- rel bias table: rbias[h][qi][ki], row stride RBS ----------------
__global__ void rel_prep(const float* __restrict__ tbl, float* __restrict__ rbias) {
  int i = blockIdx.x * 256 + threadIdx.x;
  if (i >= NH * SEQ * RBS) return;
  int h = i / (SEQ * RBS);
  int rem = i - h * SEQ * RBS;
  int qi = rem / RBS, ki = rem - qi * RBS;
  rbias[i] = (ki < SEQ) ? tbl[relidx(qi, ki) * NH + h] : 0.f;
}

// ---------------- fused QKV GEMM: [148480,768] x [768,2304] ----------------
// 128x256 tile, 8 waves (2x4), per-wave 64x64; BK=32 TRIPLE-buffered (72 KB
// LDS -> 2 blocks/CU). Stage t+2 while computing t, vmcnt(3). V-epilogue
// transposes through per-wave LDS so global stores are coalesced 16B.
#define GNT 9
#define GNWG 10440   // 1160 * 9
#define NKT 24       // 768 / 32

__global__ __launch_bounds__(512, 4)
void qkv_gemm(const ushort* __restrict__ xb, const ushort* __restrict__ Wt,
              const float* __restrict__ bq, const float* __restrict__ bv,
              ushort* __restrict__ qbuf, ushort* __restrict__ kbuf,
              ushort* __restrict__ vbuf) {
  // A[3][4096] at 0; B[3][8192] at 12288 (ushort indices). 72 KB total.
  // After the K-loop this array is reused as 8 x 4608-ushort per-wave
  // transpose scratch (8*9216 B = 73728 B, exact fit).
  __shared__ __align__(16) ushort lds[36864];

  int bid = blockIdx.x;
  int logical = (bid & 7) * 1305 + (bid >> 3);   // 10440 % 8 == 0, bijective
  int mt = logical / GNT, nt = logical - (logical / GNT) * GNT;
  int m0 = mt * 128, n0 = nt * 256;

  int tid = threadIdx.x;
  int l = tid & 63, w = tid >> 6;
  int wm = w >> 2, wn = w & 3;          // 2 x 4 wave grid
  int l15 = l & 15, l4 = l >> 4;
  int rslot = l4 ^ ((l15 >> 1) & 3);    // read-side swizzle (BK=32: 4 slots)

  // staging: thread t -> row (t>>2), stored slot (t&3); src chunk inverse-swz
  int srow = tid >> 2;                  // 0..127
  int schunk = (tid & 3) ^ ((tid >> 3) & 3);
  const ushort* aSrc  = xb + (size_t)(m0 + srow) * DMODEL + schunk * 8;
  const ushort* bSrc0 = Wt + (size_t)(n0 + srow) * DMODEL + schunk * 8;
  const ushort* bSrc1 = Wt + (size_t)(n0 + 128 + srow) * DMODEL + schunk * 8;
  int wdst = w << 9;   // w*512 ushorts (wave-contiguous dest)

#define STAGE(db, kof) do { \
    gload_lds16(aSrc  + (kof), &lds[(db) * 4096 + wdst]); \
    gload_lds16(bSrc0 + (kof), &lds[12288 + (db) * 8192 + wdst]); \
    gload_lds16(bSrc1 + (kof), &lds[12288 + (db) * 8192 + 4096 + wdst]); \
  } while (0)

  f32x4 acc[4][4];
  #pragma unroll
  for (int m = 0; m < 4; m++)
    #pragma unroll
    for (int n = 0; n < 4; n++)
      #pragma unroll
      for (int e = 0; e < 4; e++) acc[m][n][e] = 0.f;

  bf16x8 af[4], bfv[4];

#define LOADFRAG(db) do { \
    int ab_ = (db) * 4096, bb_ = 12288 + (db) * 8192; \
    _Pragma("unroll") \
    for (int i_ = 0; i_ < 4; i_++) \
      af[i_] = *reinterpret_cast<const bf16x8*>( \
          &lds[ab_ + ((wm * 64 + i_ * 16 + l15) << 5) + rslot * 8]); \
    _Pragma("unroll") \
    for (int n_ = 0; n_ < 4; n_++) \
      bfv[n_] = *reinterpret_cast<const bf16x8*>( \
          &lds[bb_ + ((wn * 64 + n_ * 16 + l15) << 5) + rslot * 8]); \
  } while (0)
#define MFMA16() do { \
    __builtin_amdgcn_s_setprio(1); \
    _Pragma("unroll") \
    for (int i_ = 0; i_ < 4; i_++) \
      _Pragma("unroll") \
      for (int n_ = 0; n_ < 4; n_++) \
        acc[i_][n_] = __builtin_amdgcn_mfma_f32_16x16x32_bf16( \
            af[i_], bfv[n_], acc[i_][n_], 0, 0, 0); \
    __builtin_amdgcn_s_setprio(0); \
  } while (0)

  // prologue: stage tiles 0 and 1; wait tile 0 only (tile 1 stays in flight)
  STAGE(0, 0);
  STAGE(1, 32);
  VMCNT(3);
  __builtin_amdgcn_s_barrier();

  #pragma unroll
  for (int t = 0; t < NKT; ++t) {
    int cur = t % 3, nx2 = (t + 2) % 3;
    if (t + 2 < NKT) STAGE(nx2, (t + 2) * 32);   // deep prefetch (tile t+2)
    LOADFRAG(cur);                                // published at t-1's barrier
    MFMA16();                                     // lgkmcnt auto-inserted
    if (t < NKT - 1) {
      if (t + 2 < NKT) { VMCNT(3); }              // retire t+1; t+2 in flight
      else             { VMCNT(0); }              // tail: retire final tile
      __builtin_amdgcn_s_barrier();               // publish t+1
    }
  }

  // ---- epilogue ----
  int which = n0 / DMODEL;
  int h_[4], dh_[4];
  float bias_[4];
  #pragma unroll
  for (int nn = 0; nn < 4; nn++) {
    int col = n0 + wn * 64 + nn * 16 + l15;
    int hcol = col - which * DMODEL;
    h_[nn] = hcol >> 6; dh_[nn] = hcol & 63;
    bias_[nn] = (which == 0) ? bq[hcol] : (which == 2 ? bv[hcol] : 0.f);
  }

  if (which != 2) {
    // q / k: coalesced-enough direct stores (dh consecutive per l15)
    #pragma unroll
    for (int i = 0; i < 4; i++) {
      #pragma unroll
      for (int r = 0; r < 4; r++) {
        int row = m0 + wm * 64 + i * 16 + (l4 << 2) + r;
        int b = row / SEQ;
        int s = row - b * SEQ;
        #pragma unroll
        for (int nn = 0; nn < 4; nn++) {
          float v = acc[i][nn][r] + bias_[nn];
          size_t bh = (size_t)b * NH + h_[nn];
          if (which == 0) {
            v *= 0.125f;  // fold 1/sqrt(64)
            qbuf[(bh * SEQ + s) * HD + dh_[nn]] = f2bf(v);
          } else {
            kbuf[(bh * SEQ + s) * HD + dh_[nn]] = f2bf(v);
          }
        }
      }
    }
  } else {
    // V: transpose through per-wave LDS, then coalesced 16B stores along s.
    __syncthreads();                 // all K-loop ds_reads complete; LDS free
    ushort* T = &lds[w * 4608];      // [64 cols(dh)][72 rows(s)+pad] per wave
    #pragma unroll
    for (int i = 0; i < 4; i++) {
      #pragma unroll
      for (int nn = 0; nn < 4; nn++) {
        int cl = nn * 16 + l15;          // col_local = dh index
        int rl = i * 16 + (l4 << 2);     // row_local base (4 rows)
        ushort4 pk;
        pk.x = f2bf(acc[i][nn][0] + bias_[nn]);
        pk.y = f2bf(acc[i][nn][1] + bias_[nn]);
        pk.z = f2bf(acc[i][nn][2] + bias_[nn]);
        pk.w = f2bf(acc[i][nn][3] + bias_[nn]);
        *reinterpret_cast<ushort4*>(&T[cl * 72 + rl]) = pk;   // ds_write_b64
      }
    }
    asm volatile("s_waitcnt lgkmcnt(0)" ::: "memory");
    __builtin_amdgcn_sched_barrier(0);
    int hU = ((n0 - 2 * DMODEL) >> 6) + wn;    // uniform head for this wave
    int rowbase = m0 + wm * 64;
    #pragma unroll
    for (int c = 0; c < 8; c++) {
      uint4 vv = *reinterpret_cast<const uint4*>(&T[l * 72 + c * 8]);
      int R = rowbase + c * 8;
      int b0 = R / SEQ;
      int b7 = (R + 7) / SEQ;
      if (b0 == b7) {
        int s0 = R - b0 * SEQ;
        size_t addr = (((size_t)b0 * NH + hU) * HD + l) * SP + s0;
        *reinterpret_cast<uint4*>(vbuf + addr) = vv;   // 16B contiguous in s
      } else {
        const ushort* pv = reinterpret_cast<const ushort*>(&vv);
        #pragma unroll
        for (int e = 0; e < 8; e++) {
          int row = R + e;
          int bb = row / SEQ, ss = row - bb * SEQ;
          vbuf[(((size_t)bb * NH + hU) * HD + l) * SP + ss] = pv[e];
        }
      }
    }
  }
#undef STAGE
#undef LOADFRAG
#undef MFMA16
}

// ---------------- fused windowed attention (swapped QK, no LDS sync) --------
// block = (b, strip, head-group of 4); 256 thr; NO barriers. mask+rbias are
// folded into the MFMA accumulator INIT (no separate add pass, fewer live
// regs). plds per-wave only. XCD b-affinity: b % 8 == xcd.
#define AH 4
__global__ __launch_bounds__(256, 4)
void attn_kernel(const ushort* __restrict__ qbuf, const ushort* __restrict__ kbuf,
                 const ushort* __restrict__ vbuf, const float* __restrict__ mask,
                 const float* __restrict__ rbias, float* __restrict__ out) {
  __shared__ __align__(16) ushort plds[AH][16][SP + 8];  // 21 KB

  int id = blockIdx.x;
  int xcd = id & 7;
  int j = id >> 3;                 // 0..3839
  int b = xcd + 8 * (j / 30);      // b % 8 == xcd
  int rem = j % 30;
  int strip = rem / 3, hg = rem % 3;
  int r0 = strip * 16;

  int tid = threadIdx.x;
  int lane = tid & 63, w = tid >> 6;
  int h = hg * AH + w;             // wave -> head
  int l15 = lane & 15, l4 = lane >> 4;
  int bh = b * NH + h;

  int qi = r0 + l15;                       // this lane's query row
  int qc = (qi < SEQ) ? qi : (SEQ - 1);
  bool qok = (qi < SEQ);

  const ushort* qp = qbuf + (size_t)bh * SEQ * HD;
  const ushort* kp = kbuf + (size_t)bh * SEQ * HD;
  const ushort* vp = vbuf + (size_t)bh * HD * SP;
  const float* mrow = mask + (size_t)b * SEQ * SEQ + (size_t)qc * SEQ;
  const float* rp = rbias + (size_t)h * SEQ * RBS + (size_t)qc * RBS;

  // Q as the B-operand (col = qi)
  bf16x8 qf[2];
  if (qok) {
    qf[0] = *reinterpret_cast<const bf16x8*>(qp + qi * HD + l4 * 8);
    qf[1] = *reinterpret_cast<const bf16x8*>(qp + qi * HD + 32 + l4 * 8);
  } else {
    uint4 z = make_uint4(0, 0, 0, 0);
    qf[0] = *reinterpret_cast<bf16x8*>(&z);
    qf[1] = *reinterpret_cast<bf16x8*>(&z);
  }

  // init accumulators with mask + rel bias (-3e38 where masked); the QK
  // MFMAs then ADD the scores -- no separate bias pass needed.
  f32x4 sc[10];
  #pragma unroll
  for (int ct = 0; ct < 9; ct++) {
    int kb = ct * 16 + l4 * 4;
    f32x4u rb = *reinterpret_cast<const f32x4u*>(rp + kb);
    f32x4u mk = *reinterpret_cast<const f32x4u*>(mrow + kb);
    #pragma unroll
    for (int r = 0; r < 4; r++)
      sc[ct][r] = qok ? (mk[r] + rb[r]) : -3e38f;
  }
  {
    float iv = (l4 == 0 && qok) ? (mrow[144] + rp[144]) : -3e38f;
    sc[9][0] = iv; sc[9][1] = -3e38f; sc[9][2] = -3e38f; sc[9][3] = -3e38f;
  }

  // scores: swapped mfma(K, Q) -> C[ki][qi]; lane holds 4 consecutive ki
  #pragma unroll
  for (int ct = 0; ct < 10; ct++) {
    int krow = ct * 16 + l15;
    if (krow >= SEQ) krow = 0;   // clamp: real data, -3e38 init masks it
    bf16x8 kf0 = *reinterpret_cast<const bf16x8*>(kp + krow * HD + l4 * 8);
    bf16x8 kf1 = *reinterpret_cast<const bf16x8*>(kp + krow * HD + 32 + l4 * 8);
    sc[ct] = __builtin_amdgcn_mfma_f32_16x16x32_bf16(kf0, qf[0], sc[ct], 0, 0, 0);
    sc[ct] = __builtin_amdgcn_mfma_f32_16x16x32_bf16(kf1, qf[1], sc[ct], 0, 0, 0);
  }

  // row max over ki
  float mx = -3e38f;
  #pragma unroll
  for (int ct = 0; ct < 10; ct++)
    #pragma unroll
    for (int r = 0; r < 4; r++) mx = fmaxf(mx, sc[ct][r]);
  mx = fmaxf(mx, __shfl_xor(mx, 16, 64));
  mx = fmaxf(mx, __shfl_xor(mx, 32, 64));

  // exp + sum over ki
  float sum = 0.f;
  #pragma unroll
  for (int ct = 0; ct < 10; ct++)
    #pragma unroll
    for (int r = 0; r < 4; r++) {
      float p = __expf(sc[ct][r] - mx);
      sc[ct][r] = p;
      sum += p;
    }
  sum += __shfl_xor(sum, 16, 64);
  sum += __shfl_xor(sum, 32, 64);
  float inv = 1.f / sum;

  // P (bf16) to per-wave LDS: row = qi idx (l15), cols = ki; ushort4 stores
  #pragma unroll
  for (int ct = 0; ct < 10; ct++) {
    ushort4 pk;
    pk.x = f2bf(sc[ct][0] * inv);
    pk.y = f2bf(sc[ct][1] * inv);
    pk.z = f2bf(sc[ct][2] * inv);
    pk.w = f2bf(sc[ct][3] * inv);
    *reinterpret_cast<ushort4*>(&plds[w][l15][ct * 16 + l4 * 4]) = pk;
  }

  // PV: ctx[16 x 64]; V^T direct from global (pad cols zeroed)
  #pragma unroll
  for (int ntl = 0; ntl < 4; ntl++) {
    f32x4 pacc;
    #pragma unroll
    for (int e = 0; e < 4; e++) pacc[e] = 0.f;
    #pragma unroll
    for (int ks = 0; ks < 5; ks++) {
      bf16x8 pa = *reinterpret_cast<const bf16x8*>(
          &plds[w][l15][ks * 32 + l4 * 8]);
      bf16x8 vb = *reinterpret_cast<const bf16x8*>(
          vp + (ntl * 16 + l15) * SP + ks * 32 + l4 * 8);
      pacc = __builtin_amdgcn_mfma_f32_16x16x32_bf16(pa, vb, pacc, 0, 0, 0);
    }
    #pragma unroll
    for (int r = 0; r < 4; r++) {
      int s = r0 + l4 * 4 + r;
      if (s < SEQ)
        out[((size_t)b * SEQ + s) * DMODEL + h * HD + ntl * 16 + l15] = pacc[r];
    }
  }
}

extern "C" void kernel_launch(void* const* d_in, const int* in_sizes, int n_in,
                              void* d_out, int out_size, void* d_ws, size_t ws_size,
                              hipStream_t stream) {
  const float* x    = (const float*)d_in[0];
  const float* mask = (const float*)d_in[1];
  const float* Wq   = (const float*)d_in[2];
  const float* bq   = (const float*)d_in[3];
  const float* Wk   = (const float*)d_in[4];
  const float* Wv   = (const float*)d_in[5];
  const float* bv   = (const float*)d_in[6];
  const float* tbl  = (const float*)d_in[7];
  float* out = (float*)d_out;

  char* ws = (char*)d_ws;
  ushort* Wt = (ushort*)ws;                         // 3,538,944 B
  size_t off = (size_t)NTOT * DMODEL * 2;
  ushort* qbuf = (ushort*)(ws + off); off += (size_t)BDIM * NH * SEQ * HD * 2;
  ushort* kbuf = (ushort*)(ws + off); off += (size_t)BDIM * NH * SEQ * HD * 2;
  ushort* vbuf = (ushort*)(ws + off); off += (size_t)BDIM * NH * HD * SP * 2;
  float*  rbias = (float*)(ws + off); off += (size_t)NH * SEQ * RBS * 4 + 64;
  // ~713 MB of d_ws

  // bf16 x lives in d_out scratch (456 MB f32 out >= 228 MB bf16 x);
  // attn_kernel later overwrites every element of d_out.
  ushort* xbuf = (ushort*)d_out;

  prep_w<<<(NTOT * DMODEL + 255) / 256, 256, 0, stream>>>(Wq, Wk, Wv, Wt);
  zero_vpad<<<(BDIM * NH * HD * (SP - SEQ) + 255) / 256, 256, 0, stream>>>(vbuf);
  rel_prep<<<(NH * SEQ * RBS + 255) / 256, 256, 0, stream>>>(tbl, rbias);
  {
    size_t total = (size_t)BDIM * SEQ * DMODEL;
    x2bf<<<(int)(total / 8 / 256), 256, 0, stream>>>(x, xbuf);
  }

  qkv_gemm<<<GNWG, 512, 0, stream>>>(xbuf, Wt, bq, bv, qbuf, kbuf, vbuf);

  attn_kernel<<<BDIM * 10 * 3, 256, 0, stream>>>(qbuf, kbuf, vbuf, mask, rbias, out);
}

// Round 16
// 1496.086 us; speedup vs baseline: 1.4816x; 1.0069x over previous
//
#include <hip/hip_runtime.h>
#include <hip/hip_bf16.h>

typedef __bf16 bf16x8 __attribute__((ext_vector_type(8)));
typedef float f32x4 __attribute__((ext_vector_type(4)));
typedef float f32x4u __attribute__((ext_vector_type(4), aligned(4)));

#define NH 12
#define HD 64
#define SEQ 145
#define SP 160
#define DMODEL 768
#define NTOT 2304
#define BDIM 1024
#define RBS 148   // rbias padded row stride (4-aligned float4 rows)

// f32 -> bf16 RNE
__device__ __forceinline__ ushort f2bf(float f) {
  union { float f; uint u; } a; a.f = f;
  uint u = a.u;
  return (ushort)((u + 0x7FFFu + ((u >> 16) & 1u)) >> 16);
}

__device__ __forceinline__ int relidx(int qi, int ki) {
  if (ki == 0) return (qi == 0) ? 531 : 530;
  if (qi == 0) return 529;
  int q = qi - 1, k = ki - 1;
  int qh = q / 12, qw = q - qh * 12;
  int kh = k / 12, kw = k - kh * 12;
  return (qh - kh + 11) * 23 + (qw - kw + 11);
}

// async global->LDS, 16B per lane; lds dest = wave-uniform base + lane*16
__device__ __forceinline__ void gload_lds16(const ushort* g, ushort* l) {
  __builtin_amdgcn_global_load_lds(
      (const __attribute__((address_space(1))) void*)g,
      (__attribute__((address_space(3))) void*)l, 16, 0, 0);
}

#define VMCNT(n) do { asm volatile("s_waitcnt vmcnt(" #n ")" ::: "memory"); \
                      __builtin_amdgcn_sched_barrier(0); } while (0)

// ---------------- prep: Wt[n][k] = W_sel[k][n%768] as bf16 ----------------
__global__ void prep_w(const float* __restrict__ Wq, const float* __restrict__ Wk,
                       const float* __restrict__ Wv, ushort* __restrict__ Wt) {
  int i = blockIdx.x * 256 + threadIdx.x;
  if (i >= NTOT * DMODEL) return;
  int n = i / DMODEL, k = i - n * DMODEL;
  const float* W = (n < DMODEL) ? Wq : (n < 2 * DMODEL ? Wk : Wv);
  int c = n % DMODEL;
  Wt[i] = f2bf(W[k * DMODEL + c]);
}

// ---------------- x f32 -> bf16 (into d_out scratch) ----------------
__global__ void x2bf(const float* __restrict__ x, ushort* __restrict__ xb) {
  const size_t total = (size_t)BDIM * SEQ * DMODEL;
  size_t i = ((size_t)blockIdx.x * 256 + threadIdx.x) * 8;
  if (i >= total) return;
  float4 a = *reinterpret_cast<const float4*>(x + i);
  float4 c = *reinterpret_cast<const float4*>(x + i + 4);
  uint4 o;
  o.x = (uint)f2bf(a.x) | ((uint)f2bf(a.y) << 16);
  o.y = (uint)f2bf(a.z) | ((uint)f2bf(a.w) << 16);
  o.z = (uint)f2bf(c.x) | ((uint)f2bf(c.y) << 16);
  o.w = (uint)f2bf(c.z) | ((uint)f2bf(c.w) << 16);
  *reinterpret_cast<uint4*>(xb + i) = o;
}

// ---------------- zero pad region of transposed V buffer ----------------
__global__ void zero_vpad(ushort* __restrict__ vbuf) {
  int i = blockIdx.x * 256 + threadIdx.x;
  const int total = BDIM * NH * HD * (SP - SEQ);
  if (i >= total) return;
  int s = SEQ + i % (SP - SEQ);
  int row = i / (SP - SEQ);
  vbuf[(size_t)row * SP + s] = 0;
}

// ---------------- rel bias table: rbias[h][qi][ki], row stride RBS ----------------
__global__ void rel_prep(const float* __restrict__ tbl, float* __restrict__ rbias) {
  int i = blockIdx.x * 256 + threadIdx.x;
  if (i >= NH * SEQ * RBS) return;
  int h = i / (SEQ * RBS);
  int rem = i - h * SEQ * RBS;
  int qi = rem / RBS, ki = rem - qi * RBS;
  rbias[i] = (ki < SEQ) ? tbl[relidx(qi, ki) * NH + h] : 0.f;
}

// ---------------- fused QKV GEMM: [148480,768] x [768,2304] ----------------
// 128x256 tile, 8 waves (2x4), per-wave 64x64; BK=32 TRIPLE-buffered (72 KB
// LDS -> 2 blocks/CU). Stage t+2 while computing t, vmcnt(3). V-epilogue
// transposes through per-wave LDS so global stores are coalesced 16B.
#define GNT 9
#define GNWG 10440   // 1160 * 9
#define NKT 24       // 768 / 32

__global__ __launch_bounds__(512, 4)
void qkv_gemm(const ushort* __restrict__ xb, const ushort* __restrict__ Wt,
              const float* __restrict__ bq, const float* __restrict__ bv,
              ushort* __restrict__ qbuf, ushort* __restrict__ kbuf,
              ushort* __restrict__ vbuf) {
  // A[3][4096] at 0; B[3][8192] at 12288 (ushort indices). 72 KB total.
  // After the K-loop this array is reused as 8 x 4608-ushort per-wave
  // transpose scratch (8*9216 B = 73728 B, exact fit).
  __shared__ __align__(16) ushort lds[36864];

  int bid = blockIdx.x;
  int logical = (bid & 7) * 1305 + (bid >> 3);   // 10440 % 8 == 0, bijective
  int mt = logical / GNT, nt = logical - (logical / GNT) * GNT;
  int m0 = mt * 128, n0 = nt * 256;

  int tid = threadIdx.x;
  int l = tid & 63, w = tid >> 6;
  int wm = w >> 2, wn = w & 3;          // 2 x 4 wave grid
  int l15 = l & 15, l4 = l >> 4;
  int rslot = l4 ^ ((l15 >> 1) & 3);    // read-side swizzle (BK=32: 4 slots)

  // staging: thread t -> row (t>>2), stored slot (t&3); src chunk inverse-swz
  int srow = tid >> 2;                  // 0..127
  int schunk = (tid & 3) ^ ((tid >> 3) & 3);
  const ushort* aSrc  = xb + (size_t)(m0 + srow) * DMODEL + schunk * 8;
  const ushort* bSrc0 = Wt + (size_t)(n0 + srow) * DMODEL + schunk * 8;
  const ushort* bSrc1 = Wt + (size_t)(n0 + 128 + srow) * DMODEL + schunk * 8;
  int wdst = w << 9;   // w*512 ushorts (wave-contiguous dest)

#define STAGE(db, kof) do { \
    gload_lds16(aSrc  + (kof), &lds[(db) * 4096 + wdst]); \
    gload_lds16(bSrc0 + (kof), &lds[12288 + (db) * 8192 + wdst]); \
    gload_lds16(bSrc1 + (kof), &lds[12288 + (db) * 8192 + 4096 + wdst]); \
  } while (0)

  f32x4 acc[4][4];
  #pragma unroll
  for (int m = 0; m < 4; m++)
    #pragma unroll
    for (int n = 0; n < 4; n++)
      #pragma unroll
      for (int e = 0; e < 4; e++) acc[m][n][e] = 0.f;

  bf16x8 af[4], bfv[4];

#define LOADFRAG(db) do { \
    int ab_ = (db) * 4096, bb_ = 12288 + (db) * 8192; \
    _Pragma("unroll") \
    for (int i_ = 0; i_ < 4; i_++) \
      af[i_] = *reinterpret_cast<const bf16x8*>( \
          &lds[ab_ + ((wm * 64 + i_ * 16 + l15) << 5) + rslot * 8]); \
    _Pragma("unroll") \
    for (int n_ = 0; n_ < 4; n_++) \
      bfv[n_] = *reinterpret_cast<const bf16x8*>( \
          &lds[bb_ + ((wn * 64 + n_ * 16 + l15) << 5) + rslot * 8]); \
  } while (0)
#define MFMA16() do { \
    __builtin_amdgcn_s_setprio(1); \
    _Pragma("unroll") \
    for (int i_ = 0; i_ < 4; i_++) \
      _Pragma("unroll") \
      for (int n_ = 0; n_ < 4; n_++) \
        acc[i_][n_] = __builtin_amdgcn_mfma_f32_16x16x32_bf16( \
            af[i_], bfv[n_], acc[i_][n_], 0, 0, 0); \
    __builtin_amdgcn_s_setprio(0); \
  } while (0)

  // prologue: stage tiles 0 and 1; wait tile 0 only (tile 1 stays in flight)
  STAGE(0, 0);
  STAGE(1, 32);
  VMCNT(3);
  __builtin_amdgcn_s_barrier();

  #pragma unroll
  for (int t = 0; t < NKT; ++t) {
    int cur = t % 3, nx2 = (t + 2) % 3;
    if (t + 2 < NKT) STAGE(nx2, (t + 2) * 32);   // deep prefetch (tile t+2)
    LOADFRAG(cur);                                // published at t-1's barrier
    MFMA16();                                     // lgkmcnt auto-inserted
    if (t < NKT - 1) {
      if (t + 2 < NKT) { VMCNT(3); }              // retire t+1; t+2 in flight
      else             { VMCNT(0); }              // tail: retire final tile
      __builtin_amdgcn_s_barrier();               // publish t+1
    }
  }

  // ---- epilogue ----
  int which = n0 / DMODEL;
  int h_[4], dh_[4];
  float bias_[4];
  #pragma unroll
  for (int nn = 0; nn < 4; nn++) {
    int col = n0 + wn * 64 + nn * 16 + l15;
    int hcol = col - which * DMODEL;
    h_[nn] = hcol >> 6; dh_[nn] = hcol & 63;
    bias_[nn] = (which == 0) ? bq[hcol] : (which == 2 ? bv[hcol] : 0.f);
  }

  if (which != 2) {
    // q / k: coalesced-enough direct stores (dh consecutive per l15)
    #pragma unroll
    for (int i = 0; i < 4; i++) {
      #pragma unroll
      for (int r = 0; r < 4; r++) {
        int row = m0 + wm * 64 + i * 16 + (l4 << 2) + r;
        int b = row / SEQ;
        int s = row - b * SEQ;
        #pragma unroll
        for (int nn = 0; nn < 4; nn++) {
          float v = acc[i][nn][r] + bias_[nn];
          size_t bh = (size_t)b * NH + h_[nn];
          if (which == 0) {
            v *= 0.125f;  // fold 1/sqrt(64)
            qbuf[(bh * SEQ + s) * HD + dh_[nn]] = f2bf(v);
          } else {
            kbuf[(bh * SEQ + s) * HD + dh_[nn]] = f2bf(v);
          }
        }
      }
    }
  } else {
    // V: transpose through per-wave LDS, then coalesced 16B stores along s.
    __syncthreads();                 // all K-loop ds_reads complete; LDS free
    ushort* T = &lds[w * 4608];      // [64 cols(dh)][72 rows(s)+pad] per wave
    #pragma unroll
    for (int i = 0; i < 4; i++) {
      #pragma unroll
      for (int nn = 0; nn < 4; nn++) {
        int cl = nn * 16 + l15;          // col_local = dh index
        int rl = i * 16 + (l4 << 2);     // row_local base (4 rows)
        ushort4 pk;
        pk.x = f2bf(acc[i][nn][0] + bias_[nn]);
        pk.y = f2bf(acc[i][nn][1] + bias_[nn]);
        pk.z = f2bf(acc[i][nn][2] + bias_[nn]);
        pk.w = f2bf(acc[i][nn][3] + bias_[nn]);
        *reinterpret_cast<ushort4*>(&T[cl * 72 + rl]) = pk;   // ds_write_b64
      }
    }
    asm volatile("s_waitcnt lgkmcnt(0)" ::: "memory");
    __builtin_amdgcn_sched_barrier(0);
    int hU = ((n0 - 2 * DMODEL) >> 6) + wn;    // uniform head for this wave
    int rowbase = m0 + wm * 64;
    #pragma unroll
    for (int c = 0; c < 8; c++) {
      uint4 vv = *reinterpret_cast<const uint4*>(&T[l * 72 + c * 8]);
      int R = rowbase + c * 8;
      int b0 = R / SEQ;
      int b7 = (R + 7) / SEQ;
      if (b0 == b7) {
        int s0 = R - b0 * SEQ;
        size_t addr = (((size_t)b0 * NH + hU) * HD + l) * SP + s0;
        *reinterpret_cast<uint4*>(vbuf + addr) = vv;   // 16B contiguous in s
      } else {
        const ushort* pv = reinterpret_cast<const ushort*>(&vv);
        #pragma unroll
        for (int e = 0; e < 8; e++) {
          int row = R + e;
          int bb = row / SEQ, ss = row - bb * SEQ;
          vbuf[(((size_t)bb * NH + hU) * HD + l) * SP + ss] = pv[e];
        }
      }
    }
  }
#undef STAGE
#undef LOADFRAG
#undef MFMA16
}

// ---------------- fused windowed attention (swapped QK, no LDS sync) --------
// block = (b, strip, head-group of 4); 256 thr; NO barriers. mask+rbias folded
// into MFMA accumulator init. launch_bounds(256,2): VGPR cap ~128 so the
// compiler can keep ~10 fragment loads in flight (sc[10]+qf are live all
// kernel; at cap 64 only 1-2 loads fit -> full serialization, r13/r15 data).
#define AH 4
__global__ __launch_bounds__(256, 2)
void attn_kernel(const ushort* __restrict__ qbuf, const ushort* __restrict__ kbuf,
                 const ushort* __restrict__ vbuf, const float* __restrict__ mask,
                 const float* __restrict__ rbias, float* __restrict__ out) {
  __shared__ __align__(16) ushort plds[AH][16][SP + 8];  // 21 KB

  int id = blockIdx.x;
  int xcd = id & 7;
  int j = id >> 3;                 // 0..3839
  int b = xcd + 8 * (j / 30);      // b % 8 == xcd
  int rem = j % 30;
  int strip = rem / 3, hg = rem % 3;
  int r0 = strip * 16;

  int tid = threadIdx.x;
  int lane = tid & 63, w = tid >> 6;
  int h = hg * AH + w;             // wave -> head
  int l15 = lane & 15, l4 = lane >> 4;
  int bh = b * NH + h;

  int qi = r0 + l15;                       // this lane's query row
  int qc = (qi < SEQ) ? qi : (SEQ - 1);
  bool qok = (qi < SEQ);

  const ushort* qp = qbuf + (size_t)bh * SEQ * HD;
  const ushort* kp = kbuf + (size_t)bh * SEQ * HD;
  const ushort* vp = vbuf + (size_t)bh * HD * SP;
  const float* mrow = mask + (size_t)b * SEQ * SEQ + (size_t)qc * SEQ;
  const float* rp = rbias + (size_t)h * SEQ * RBS + (size_t)qc * RBS;

  // Q as the B-operand (col = qi)
  bf16x8 qf[2];
  if (qok) {
    qf[0] = *reinterpret_cast<const bf16x8*>(qp + qi * HD + l4 * 8);
    qf[1] = *reinterpret_cast<const bf16x8*>(qp + qi * HD + 32 + l4 * 8);
  } else {
    uint4 z = make_uint4(0, 0, 0, 0);
    qf[0] = *reinterpret_cast<bf16x8*>(&z);
    qf[1] = *reinterpret_cast<bf16x8*>(&z);
  }

  // init accumulators with mask + rel bias (-3e38 where masked); the QK
  // MFMAs then ADD the scores -- no separate bias pass needed.
  f32x4 sc[10];
  #pragma unroll
  for (int ct = 0; ct < 9; ct++) {
    int kb = ct * 16 + l4 * 4;
    f32x4u rb = *reinterpret_cast<const f32x4u*>(rp + kb);
    f32x4u mk = *reinterpret_cast<const f32x4u*>(mrow + kb);
    #pragma unroll
    for (int r = 0; r < 4; r++)
      sc[ct][r] = qok ? (mk[r] + rb[r]) : -3e38f;
  }
  {
    float iv = (l4 == 0 && qok) ? (mrow[144] + rp[144]) : -3e38f;
    sc[9][0] = iv; sc[9][1] = -3e38f; sc[9][2] = -3e38f; sc[9][3] = -3e38f;
  }

  // scores: swapped mfma(K, Q) -> C[ki][qi]; lane holds 4 consecutive ki
  #pragma unroll
  for (int ct = 0; ct < 10; ct++) {
    int krow = ct * 16 + l15;
    if (krow >= SEQ) krow = 0;   // clamp: real data, -3e38 init masks it
    bf16x8 kf0 = *reinterpret_cast<const bf16x8*>(kp + krow * HD + l4 * 8);
    bf16x8 kf1 = *reinterpret_cast<const bf16x8*>(kp + krow * HD + 32 + l4 * 8);
    sc[ct] = __builtin_amdgcn_mfma_f32_16x16x32_bf16(kf0, qf[0], sc[ct], 0, 0, 0);
    sc[ct] = __builtin_amdgcn_mfma_f32_16x16x32_bf16(kf1, qf[1], sc[ct], 0, 0, 0);
  }

  // row max over ki
  float mx = -3e38f;
  #pragma unroll
  for (int ct = 0; ct < 10; ct++)
    #pragma unroll
    for (int r = 0; r < 4; r++) mx = fmaxf(mx, sc[ct][r]);
  mx = fmaxf(mx, __shfl_xor(mx, 16, 64));
  mx = fmaxf(mx, __shfl_xor(mx, 32, 64));

  // exp + sum over ki
  float sum = 0.f;
  #pragma unroll
  for (int ct = 0; ct < 10; ct++)
    #pragma unroll
    for (int r = 0; r < 4; r++) {
      float p = __expf(sc[ct][r] - mx);
      sc[ct][r] = p;
      sum += p;
    }
  sum += __shfl_xor(sum, 16, 64);
  sum += __shfl_xor(sum, 32, 64);
  float inv = 1.f / sum;

  // P (bf16) to per-wave LDS: row = qi idx (l15), cols = ki; ushort4 stores
  #pragma unroll
  for (int ct = 0; ct < 10; ct++) {
    ushort4 pk;
    pk.x = f2bf(sc[ct][0] * inv);
    pk.y = f2bf(sc[ct][1] * inv);
    pk.z = f2bf(sc[ct][2] * inv);
    pk.w = f2bf(sc[ct][3] * inv);
    *reinterpret_cast<ushort4*>(&plds[w][l15][ct * 16 + l4 * 4]) = pk;
  }

  // PV: ctx[16 x 64]; V^T direct from global (pad cols zeroed)
  #pragma unroll
  for (int ntl = 0; ntl < 4; ntl++) {
    f32x4 pacc;
    #pragma unroll
    for (int e = 0; e < 4; e++) pacc[e] = 0.f;
    #pragma unroll
    for (int ks = 0; ks < 5; ks++) {
      bf16x8 pa = *reinterpret_cast<const bf16x8*>(
          &plds[w][l15][ks * 32 + l4 * 8]);
      bf16x8 vb = *reinterpret_cast<const bf16x8*>(
          vp + (ntl * 16 + l15) * SP + ks * 32 + l4 * 8);
      pacc = __builtin_amdgcn_mfma_f32_16x16x32_bf16(pa, vb, pacc, 0, 0, 0);
    }
    #pragma unroll
    for (int r = 0; r < 4; r++) {
      int s = r0 + l4 * 4 + r;
      if (s < SEQ)
        out[((size_t)b * SEQ + s) * DMODEL + h * HD + ntl * 16 + l15] = pacc[r];
    }
  }
}

extern "C" void kernel_launch(void* const* d_in, const int* in_sizes, int n_in,
                              void* d_out, int out_size, void* d_ws, size_t ws_size,
                              hipStream_t stream) {
  const float* x    = (const float*)d_in[0];
  const float* mask = (const float*)d_in[1];
  const float* Wq   = (const float*)d_in[2];
  const float* bq   = (const float*)d_in[3];
  const float* Wk   = (const float*)d_in[4];
  const float* Wv   = (const float*)d_in[5];
  const float* bv   = (const float*)d_in[6];
  const float* tbl  = (const float*)d_in[7];
  float* out = (float*)d_out;

  char* ws = (char*)d_ws;
  ushort* Wt = (ushort*)ws;                         // 3,538,944 B
  size_t off = (size_t)NTOT * DMODEL * 2;
  ushort* qbuf = (ushort*)(ws + off); off += (size_t)BDIM * NH * SEQ * HD * 2;
  ushort* kbuf = (ushort*)(ws + off); off += (size_t)BDIM * NH * SEQ * HD * 2;
  ushort* vbuf = (ushort*)(ws + off); off += (size_t)BDIM * NH * HD * SP * 2;
  float*  rbias = (float*)(ws + off); off += (size_t)NH * SEQ * RBS * 4 + 64;
  // ~713 MB of d_ws

  // bf16 x lives in d_out scratch (456 MB f32 out >= 228 MB bf16 x);
  // attn_kernel later overwrites every element of d_out.
  ushort* xbuf = (ushort*)d_out;

  prep_w<<<(NTOT * DMODEL + 255) / 256, 256, 0, stream>>>(Wq, Wk, Wv, Wt);
  zero_vpad<<<(BDIM * NH * HD * (SP - SEQ) + 255) / 256, 256, 0, stream>>>(vbuf);
  rel_prep<<<(NH * SEQ * RBS + 255) / 256, 256, 0, stream>>>(tbl, rbias);
  {
    size_t total = (size_t)BDIM * SEQ * DMODEL;
    x2bf<<<(int)(total / 8 / 256), 256, 0, stream>>>(x, xbuf);
  }

  qkv_gemm<<<GNWG, 512, 0, stream>>>(xbuf, Wt, bq, bv, qbuf, kbuf, vbuf);

  attn_kernel<<<BDIM * 10 * 3, 256, 0, stream>>>(qbuf, kbuf, vbuf, mask, rbias, out);
}

// Round 17
// 1438.123 us; speedup vs baseline: 1.5413x; 1.0403x over previous
//
#include <hip/hip_runtime.h>
#include <hip/hip_bf16.h>

typedef __bf16 bf16x8 __attribute__((ext_vector_type(8)));
typedef float f32x4 __attribute__((ext_vector_type(4)));
typedef float f32x4u __attribute__((ext_vector_type(4), aligned(4)));

#define NH 12
#define HD 64
#define SEQ 145
#define SP 160
#define DMODEL 768
#define NTOT 2304
#define BDIM 1024
#define RBS 148   // rbias padded row stride (4-aligned float4 rows)

// f32 -> bf16 RNE
__device__ __forceinline__ ushort f2bf(float f) {
  union { float f; uint u; } a; a.f = f;
  uint u = a.u;
  return (ushort)((u + 0x7FFFu + ((u >> 16) & 1u)) >> 16);
}

__device__ __forceinline__ int relidx(int qi, int ki) {
  if (ki == 0) return (qi == 0) ? 531 : 530;
  if (qi == 0) return 529;
  int q = qi - 1, k = ki - 1;
  int qh = q / 12, qw = q - qh * 12;
  int kh = k / 12, kw = k - kh * 12;
  return (qh - kh + 11) * 23 + (qw - kw + 11);
}

// async global->LDS, 16B per lane; lds dest = wave-uniform base + lane*16
__device__ __forceinline__ void gload_lds16(const ushort* g, ushort* l) {
  __builtin_amdgcn_global_load_lds(
      (const __attribute__((address_space(1))) void*)g,
      (__attribute__((address_space(3))) void*)l, 16, 0, 0);
}

#define VMCNT(n) do { asm volatile("s_waitcnt vmcnt(" #n ")" ::: "memory"); \
                      __builtin_amdgcn_sched_barrier(0); } while (0)

// ---------------- prep: Wt[n][k] = W_sel[k][n%768] as bf16 ----------------
__global__ void prep_w(const float* __restrict__ Wq, const float* __restrict__ Wk,
                       const float* __restrict__ Wv, ushort* __restrict__ Wt) {
  int i = blockIdx.x * 256 + threadIdx.x;
  if (i >= NTOT * DMODEL) return;
  int n = i / DMODEL, k = i - n * DMODEL;
  const float* W = (n < DMODEL) ? Wq : (n < 2 * DMODEL ? Wk : Wv);
  int c = n % DMODEL;
  Wt[i] = f2bf(W[k * DMODEL + c]);
}

// ---------------- x f32 -> bf16 (into d_out scratch) ----------------
__global__ void x2bf(const float* __restrict__ x, ushort* __restrict__ xb) {
  const size_t total = (size_t)BDIM * SEQ * DMODEL;
  size_t i = ((size_t)blockIdx.x * 256 + threadIdx.x) * 8;
  if (i >= total) return;
  float4 a = *reinterpret_cast<const float4*>(x + i);
  float4 c = *reinterpret_cast<const float4*>(x + i + 4);
  uint4 o;
  o.x = (uint)f2bf(a.x) | ((uint)f2bf(a.y) << 16);
  o.y = (uint)f2bf(a.z) | ((uint)f2bf(a.w) << 16);
  o.z = (uint)f2bf(c.x) | ((uint)f2bf(c.y) << 16);
  o.w = (uint)f2bf(c.z) | ((uint)f2bf(c.w) << 16);
  *reinterpret_cast<uint4*>(xb + i) = o;
}

// ---------------- zero pad region of transposed V buffer ----------------
__global__ void zero_vpad(ushort* __restrict__ vbuf) {
  int i = blockIdx.x * 256 + threadIdx.x;
  const int total = BDIM * NH * HD * (SP - SEQ);
  if (i >= total) return;
  int s = SEQ + i % (SP - SEQ);
  int row = i / (SP - SEQ);
  vbuf[(size_t)row * SP + s] = 0;
}

// ---------------- rel bias table: rbias[h][qi][ki], row stride RBS ----------------
__global__ void rel_prep(const float* __restrict__ tbl, float* __restrict__ rbias) {
  int i = blockIdx.x * 256 + threadIdx.x;
  if (i >= NH * SEQ * RBS) return;
  int h = i / (SEQ * RBS);
  int rem = i - h * SEQ * RBS;
  int qi = rem / RBS, ki = rem - qi * RBS;
  rbias[i] = (ki < SEQ) ? tbl[relidx(qi, ki) * NH + h] : 0.f;
}

// ---------------- fused QKV GEMM: [148480,768] x [768,2304] ----------------
// 128x256 tile, 8 waves (2x4), per-wave 64x64; BK=32 TRIPLE-buffered (72 KB
// LDS -> 2 blocks/CU). Stage t+2 while computing t, vmcnt(3). V-epilogue
// transposes through per-wave LDS so global stores are coalesced 16B.
#define GNT 9
#define GNWG 10440   // 1160 * 9
#define NKT 24       // 768 / 32

__global__ __launch_bounds__(512, 4)
void qkv_gemm(const ushort* __restrict__ xb, const ushort* __restrict__ Wt,
              const float* __restrict__ bq, const float* __restrict__ bv,
              ushort* __restrict__ qbuf, ushort* __restrict__ kbuf,
              ushort* __restrict__ vbuf) {
  // A[3][4096] at 0; B[3][8192] at 12288 (ushort indices). 72 KB total.
  // After the K-loop this array is reused as 8 x 4608-ushort per-wave
  // transpose scratch (8*9216 B = 73728 B, exact fit).
  __shared__ __align__(16) ushort lds[36864];

  int bid = blockIdx.x;
  int logical = (bid & 7) * 1305 + (bid >> 3);   // 10440 % 8 == 0, bijective
  int mt = logical / GNT, nt = logical - (logical / GNT) * GNT;
  int m0 = mt * 128, n0 = nt * 256;

  int tid = threadIdx.x;
  int l = tid & 63, w = tid >> 6;
  int wm = w >> 2, wn = w & 3;          // 2 x 4 wave grid
  int l15 = l & 15, l4 = l >> 4;
  int rslot = l4 ^ ((l15 >> 1) & 3);    // read-side swizzle (BK=32: 4 slots)

  // staging: thread t -> row (t>>2), stored slot (t&3); src chunk inverse-swz
  int srow = tid >> 2;                  // 0..127
  int schunk = (tid & 3) ^ ((tid >> 3) & 3);
  const ushort* aSrc  = xb + (size_t)(m0 + srow) * DMODEL + schunk * 8;
  const ushort* bSrc0 = Wt + (size_t)(n0 + srow) * DMODEL + schunk * 8;
  const ushort* bSrc1 = Wt + (size_t)(n0 + 128 + srow) * DMODEL + schunk * 8;
  int wdst = w << 9;   // w*512 ushorts (wave-contiguous dest)

#define STAGE(db, kof) do { \
    gload_lds16(aSrc  + (kof), &lds[(db) * 4096 + wdst]); \
    gload_lds16(bSrc0 + (kof), &lds[12288 + (db) * 8192 + wdst]); \
    gload_lds16(bSrc1 + (kof), &lds[12288 + (db) * 8192 + 4096 + wdst]); \
  } while (0)

  f32x4 acc[4][4];
  #pragma unroll
  for (int m = 0; m < 4; m++)
    #pragma unroll
    for (int n = 0; n < 4; n++)
      #pragma unroll
      for (int e = 0; e < 4; e++) acc[m][n][e] = 0.f;

  bf16x8 af[4], bfv[4];

#define LOADFRAG(db) do { \
    int ab_ = (db) * 4096, bb_ = 12288 + (db) * 8192; \
    _Pragma("unroll") \
    for (int i_ = 0; i_ < 4; i_++) \
      af[i_] = *reinterpret_cast<const bf16x8*>( \
          &lds[ab_ + ((wm * 64 + i_ * 16 + l15) << 5) + rslot * 8]); \
    _Pragma("unroll") \
    for (int n_ = 0; n_ < 4; n_++) \
      bfv[n_] = *reinterpret_cast<const bf16x8*>( \
          &lds[bb_ + ((wn * 64 + n_ * 16 + l15) << 5) + rslot * 8]); \
  } while (0)
#define MFMA16() do { \
    __builtin_amdgcn_s_setprio(1); \
    _Pragma("unroll") \
    for (int i_ = 0; i_ < 4; i_++) \
      _Pragma("unroll") \
      for (int n_ = 0; n_ < 4; n_++) \
        acc[i_][n_] = __builtin_amdgcn_mfma_f32_16x16x32_bf16( \
            af[i_], bfv[n_], acc[i_][n_], 0, 0, 0); \
    __builtin_amdgcn_s_setprio(0); \
  } while (0)

  // prologue: stage tiles 0 and 1; wait tile 0 only (tile 1 stays in flight)
  STAGE(0, 0);
  STAGE(1, 32);
  VMCNT(3);
  __builtin_amdgcn_s_barrier();

  #pragma unroll
  for (int t = 0; t < NKT; ++t) {
    int cur = t % 3, nx2 = (t + 2) % 3;
    if (t + 2 < NKT) STAGE(nx2, (t + 2) * 32);   // deep prefetch (tile t+2)
    LOADFRAG(cur);                                // published at t-1's barrier
    MFMA16();                                     // lgkmcnt auto-inserted
    if (t < NKT - 1) {
      if (t + 2 < NKT) { VMCNT(3); }              // retire t+1; t+2 in flight
      else             { VMCNT(0); }              // tail: retire final tile
      __builtin_amdgcn_s_barrier();               // publish t+1
    }
  }

  // ---- epilogue ----
  int which = n0 / DMODEL;
  int h_[4], dh_[4];
  float bias_[4];
  #pragma unroll
  for (int nn = 0; nn < 4; nn++) {
    int col = n0 + wn * 64 + nn * 16 + l15;
    int hcol = col - which * DMODEL;
    h_[nn] = hcol >> 6; dh_[nn] = hcol & 63;
    bias_[nn] = (which == 0) ? bq[hcol] : (which == 2 ? bv[hcol] : 0.f);
  }

  if (which != 2) {
    // q / k: coalesced-enough direct stores (dh consecutive per l15)
    #pragma unroll
    for (int i = 0; i < 4; i++) {
      #pragma unroll
      for (int r = 0; r < 4; r++) {
        int row = m0 + wm * 64 + i * 16 + (l4 << 2) + r;
        int b = row / SEQ;
        int s = row - b * SEQ;
        #pragma unroll
        for (int nn = 0; nn < 4; nn++) {
          float v = acc[i][nn][r] + bias_[nn];
          size_t bh = (size_t)b * NH + h_[nn];
          if (which == 0) {
            v *= 0.125f;  // fold 1/sqrt(64)
            qbuf[(bh * SEQ + s) * HD + dh_[nn]] = f2bf(v);
          } else {
            kbuf[(bh * SEQ + s) * HD + dh_[nn]] = f2bf(v);
          }
        }
      }
    }
  } else {
    // V: transpose through per-wave LDS, then coalesced 16B stores along s.
    __syncthreads();                 // all K-loop ds_reads complete; LDS free
    ushort* T = &lds[w * 4608];      // [64 cols(dh)][72 rows(s)+pad] per wave
    #pragma unroll
    for (int i = 0; i < 4; i++) {
      #pragma unroll
      for (int nn = 0; nn < 4; nn++) {
        int cl = nn * 16 + l15;          // col_local = dh index
        int rl = i * 16 + (l4 << 2);     // row_local base (4 rows)
        ushort4 pk;
        pk.x = f2bf(acc[i][nn][0] + bias_[nn]);
        pk.y = f2bf(acc[i][nn][1] + bias_[nn]);
        pk.z = f2bf(acc[i][nn][2] + bias_[nn]);
        pk.w = f2bf(acc[i][nn][3] + bias_[nn]);
        *reinterpret_cast<ushort4*>(&T[cl * 72 + rl]) = pk;   // ds_write_b64
      }
    }
    asm volatile("s_waitcnt lgkmcnt(0)" ::: "memory");
    __builtin_amdgcn_sched_barrier(0);
    int hU = ((n0 - 2 * DMODEL) >> 6) + wn;    // uniform head for this wave
    int rowbase = m0 + wm * 64;
    #pragma unroll
    for (int c = 0; c < 8; c++) {
      uint4 vv = *reinterpret_cast<const uint4*>(&T[l * 72 + c * 8]);
      int R = rowbase + c * 8;
      int b0 = R / SEQ;
      int b7 = (R + 7) / SEQ;
      if (b0 == b7) {
        int s0 = R - b0 * SEQ;
        size_t addr = (((size_t)b0 * NH + hU) * HD + l) * SP + s0;
        *reinterpret_cast<uint4*>(vbuf + addr) = vv;   // 16B contiguous in s
      } else {
        const ushort* pv = reinterpret_cast<const ushort*>(&vv);
        #pragma unroll
        for (int e = 0; e < 8; e++) {
          int row = R + e;
          int bb = row / SEQ, ss = row - bb * SEQ;
          vbuf[(((size_t)bb * NH + hU) * HD + l) * SP + ss] = pv[e];
        }
      }
    }
  }
#undef STAGE
#undef LOADFRAG
#undef MFMA16
}

// ---------------- fused windowed attention (swapped QK, explicit MLP) -------
// block = (b, strip, head-group of 4); 256 thr; NO barriers. All K/V fragment
// loads issued in EXPLICIT register windows (10-12 in flight) ahead of their
// consuming MFMAs, pinned with sched_barrier -- the compiler refuses to widen
// the window on its own (r13/r15/r16: 730us flat, serialized loads).
#define AH 4
__global__ __launch_bounds__(256, 2)
void attn_kernel(const ushort* __restrict__ qbuf, const ushort* __restrict__ kbuf,
                 const ushort* __restrict__ vbuf, const float* __restrict__ mask,
                 const float* __restrict__ rbias, float* __restrict__ out) {
  __shared__ __align__(16) ushort plds[AH][16][SP + 8];  // 21 KB

  int id = blockIdx.x;
  int xcd = id & 7;
  int j = id >> 3;                 // 0..3839
  int b = xcd + 8 * (j / 30);      // b % 8 == xcd
  int rem = j % 30;
  int strip = rem / 3, hg = rem % 3;
  int r0 = strip * 16;

  int tid = threadIdx.x;
  int lane = tid & 63, w = tid >> 6;
  int h = hg * AH + w;             // wave -> head
  int l15 = lane & 15, l4 = lane >> 4;
  int bh = b * NH + h;

  int qi = r0 + l15;                       // this lane's query row
  int qc = (qi < SEQ) ? qi : (SEQ - 1);
  bool qok = (qi < SEQ);

  const ushort* qp = qbuf + (size_t)bh * SEQ * HD;
  const ushort* kp = kbuf + (size_t)bh * SEQ * HD;
  const ushort* vp = vbuf + (size_t)bh * HD * SP;
  const float* mrow = mask + (size_t)b * SEQ * SEQ + (size_t)qc * SEQ;
  const float* rp = rbias + (size_t)h * SEQ * RBS + (size_t)qc * RBS;

  // ---- phase 1: issue Q + K(ct0..4) loads (12 in flight) ----
  uint4 qr0, qr1;
  if (qok) {
    qr0 = *reinterpret_cast<const uint4*>(qp + qi * HD + l4 * 8);
    qr1 = *reinterpret_cast<const uint4*>(qp + qi * HD + 32 + l4 * 8);
  } else {
    qr0 = make_uint4(0, 0, 0, 0); qr1 = qr0;
  }
  uint4 kfa[10];
  #pragma unroll
  for (int ct = 0; ct < 5; ct++) {
    int krow = ct * 16 + l15;            // <= 79 < SEQ: no clamp
    kfa[2 * ct]     = *reinterpret_cast<const uint4*>(kp + krow * HD + l4 * 8);
    kfa[2 * ct + 1] = *reinterpret_cast<const uint4*>(kp + krow * HD + 32 + l4 * 8);
  }
  // sc init ct0..4 (mask+rbias fold into accumulator)
  f32x4 sc[10];
  #pragma unroll
  for (int ct = 0; ct < 5; ct++) {
    int kb = ct * 16 + l4 * 4;
    f32x4u rb = *reinterpret_cast<const f32x4u*>(rp + kb);
    f32x4u mk = *reinterpret_cast<const f32x4u*>(mrow + kb);
    #pragma unroll
    for (int r = 0; r < 4; r++)
      sc[ct][r] = qok ? (mk[r] + rb[r]) : -3e38f;
  }
  // ---- phase 2: issue K(ct5..9) before consuming half A ----
  uint4 kfb[10];
  #pragma unroll
  for (int ct = 5; ct < 10; ct++) {
    int krow = ct * 16 + l15;
    if (krow >= SEQ) krow = 0;           // clamp: masked via -3e38 init
    kfb[2 * (ct - 5)]     = *reinterpret_cast<const uint4*>(kp + krow * HD + l4 * 8);
    kfb[2 * (ct - 5) + 1] = *reinterpret_cast<const uint4*>(kp + krow * HD + 32 + l4 * 8);
  }
  __builtin_amdgcn_sched_barrier(0);

  // ---- MFMA A (one exposed latency for all of kfa) ----
  bf16x8 qf0 = *reinterpret_cast<bf16x8*>(&qr0);
  bf16x8 qf1 = *reinterpret_cast<bf16x8*>(&qr1);
  #pragma unroll
  for (int ct = 0; ct < 5; ct++) {
    sc[ct] = __builtin_amdgcn_mfma_f32_16x16x32_bf16(
        *reinterpret_cast<bf16x8*>(&kfa[2 * ct]), qf0, sc[ct], 0, 0, 0);
    sc[ct] = __builtin_amdgcn_mfma_f32_16x16x32_bf16(
        *reinterpret_cast<bf16x8*>(&kfa[2 * ct + 1]), qf1, sc[ct], 0, 0, 0);
  }
  // sc init ct5..9
  #pragma unroll
  for (int ct = 5; ct < 9; ct++) {
    int kb = ct * 16 + l4 * 4;
    f32x4u rb = *reinterpret_cast<const f32x4u*>(rp + kb);
    f32x4u mk = *reinterpret_cast<const f32x4u*>(mrow + kb);
    #pragma unroll
    for (int r = 0; r < 4; r++)
      sc[ct][r] = qok ? (mk[r] + rb[r]) : -3e38f;
  }
  {
    float iv = (l4 == 0 && qok) ? (mrow[144] + rp[144]) : -3e38f;
    sc[9][0] = iv; sc[9][1] = -3e38f; sc[9][2] = -3e38f; sc[9][3] = -3e38f;
  }
  // ---- MFMA B ----
  #pragma unroll
  for (int ct = 5; ct < 10; ct++) {
    sc[ct] = __builtin_amdgcn_mfma_f32_16x16x32_bf16(
        *reinterpret_cast<bf16x8*>(&kfb[2 * (ct - 5)]), qf0, sc[ct], 0, 0, 0);
    sc[ct] = __builtin_amdgcn_mfma_f32_16x16x32_bf16(
        *reinterpret_cast<bf16x8*>(&kfb[2 * (ct - 5) + 1]), qf1, sc[ct], 0, 0, 0);
  }
  __builtin_amdgcn_sched_barrier(0);

  // ---- issue V(ntl0,1) now; softmax VALU below hides their latency ----
  uint4 vba[10];
  #pragma unroll
  for (int t = 0; t < 10; t++) {
    int ntl = t / 5, ks = t % 5;
    vba[t] = *reinterpret_cast<const uint4*>(
        vp + (ntl * 16 + l15) * SP + ks * 32 + l4 * 8);
  }
  __builtin_amdgcn_sched_barrier(0);

  // ---- softmax: row max, exp, sum over ki ----
  float mx = -3e38f;
  #pragma unroll
  for (int ct = 0; ct < 10; ct++)
    #pragma unroll
    for (int r = 0; r < 4; r++) mx = fmaxf(mx, sc[ct][r]);
  mx = fmaxf(mx, __shfl_xor(mx, 16, 64));
  mx = fmaxf(mx, __shfl_xor(mx, 32, 64));
  float sum = 0.f;
  #pragma unroll
  for (int ct = 0; ct < 10; ct++)
    #pragma unroll
    for (int r = 0; r < 4; r++) {
      float p = __expf(sc[ct][r] - mx);
      sc[ct][r] = p;
      sum += p;
    }
  sum += __shfl_xor(sum, 16, 64);
  sum += __shfl_xor(sum, 32, 64);
  float inv = 1.f / sum;

  // ---- P (bf16) to per-wave LDS; sc dies here ----
  #pragma unroll
  for (int ct = 0; ct < 10; ct++) {
    ushort4 pk;
    pk.x = f2bf(sc[ct][0] * inv);
    pk.y = f2bf(sc[ct][1] * inv);
    pk.z = f2bf(sc[ct][2] * inv);
    pk.w = f2bf(sc[ct][3] * inv);
    *reinterpret_cast<ushort4*>(&plds[w][l15][ct * 16 + l4 * 4]) = pk;
  }

  // ---- issue V(ntl2,3) ----
  uint4 vbb[10];
  #pragma unroll
  for (int t = 0; t < 10; t++) {
    int ntl = 2 + t / 5, ks = t % 5;
    vbb[t] = *reinterpret_cast<const uint4*>(
        vp + (ntl * 16 + l15) * SP + ks * 32 + l4 * 8);
  }
  __builtin_amdgcn_sched_barrier(0);

  // ---- PV: ntl 0,1 from vba; ntl 2,3 from vbb ----
  #pragma unroll
  for (int ntl = 0; ntl < 2; ntl++) {
    f32x4 pacc;
    #pragma unroll
    for (int e = 0; e < 4; e++) pacc[e] = 0.f;
    #pragma unroll
    for (int ks = 0; ks < 5; ks++) {
      bf16x8 pa = *reinterpret_cast<const bf16x8*>(
          &plds[w][l15][ks * 32 + l4 * 8]);
      pacc = __builtin_amdgcn_mfma_f32_16x16x32_bf16(
          pa, *reinterpret_cast<bf16x8*>(&vba[ntl * 5 + ks]), pacc, 0, 0, 0);
    }
    #pragma unroll
    for (int r = 0; r < 4; r++) {
      int s = r0 + l4 * 4 + r;
      if (s < SEQ)
        out[((size_t)b * SEQ + s) * DMODEL + h * HD + ntl * 16 + l15] = pacc[r];
    }
  }
  #pragma unroll
  for (int ntl = 2; ntl < 4; ntl++) {
    f32x4 pacc;
    #pragma unroll
    for (int e = 0; e < 4; e++) pacc[e] = 0.f;
    #pragma unroll
    for (int ks = 0; ks < 5; ks++) {
      bf16x8 pa = *reinterpret_cast<const bf16x8*>(
          &plds[w][l15][ks * 32 + l4 * 8]);
      pacc = __builtin_amdgcn_mfma_f32_16x16x32_bf16(
          pa, *reinterpret_cast<bf16x8*>(&vbb[(ntl - 2) * 5 + ks]), pacc, 0, 0, 0);
    }
    #pragma unroll
    for (int r = 0; r < 4; r++) {
      int s = r0 + l4 * 4 + r;
      if (s < SEQ)
        out[((size_t)b * SEQ + s) * DMODEL + h * HD + ntl * 16 + l15] = pacc[r];
    }
  }
}

extern "C" void kernel_launch(void* const* d_in, const int* in_sizes, int n_in,
                              void* d_out, int out_size, void* d_ws, size_t ws_size,
                              hipStream_t stream) {
  const float* x    = (const float*)d_in[0];
  const float* mask = (const float*)d_in[1];
  const float* Wq   = (const float*)d_in[2];
  const float* bq   = (const float*)d_in[3];
  const float* Wk   = (const float*)d_in[4];
  const float* Wv   = (const float*)d_in[5];
  const float* bv   = (const float*)d_in[6];
  const float* tbl  = (const float*)d_in[7];
  float* out = (float*)d_out;

  char* ws = (char*)d_ws;
  ushort* Wt = (ushort*)ws;                         // 3,538,944 B
  size_t off = (size_t)NTOT * DMODEL * 2;
  ushort* qbuf = (ushort*)(ws + off); off += (size_t)BDIM * NH * SEQ * HD * 2;
  ushort* kbuf = (ushort*)(ws + off); off += (size_t)BDIM * NH * SEQ * HD * 2;
  ushort* vbuf = (ushort*)(ws + off); off += (size_t)BDIM * NH * HD * SP * 2;
  float*  rbias = (float*)(ws + off); off += (size_t)NH * SEQ * RBS * 4 + 64;
  // ~713 MB of d_ws

  // bf16 x lives in d_out scratch (456 MB f32 out >= 228 MB bf16 x);
  // attn_kernel later overwrites every element of d_out.
  ushort* xbuf = (ushort*)d_out;

  prep_w<<<(NTOT * DMODEL + 255) / 256, 256, 0, stream>>>(Wq, Wk, Wv, Wt);
  zero_vpad<<<(BDIM * NH * HD * (SP - SEQ) + 255) / 256, 256, 0, stream>>>(vbuf);
  rel_prep<<<(NH * SEQ * RBS + 255) / 256, 256, 0, stream>>>(tbl, rbias);
  {
    size_t total = (size_t)BDIM * SEQ * DMODEL;
    x2bf<<<(int)(total / 8 / 256), 256, 0, stream>>>(x, xbuf);
  }

  qkv_gemm<<<GNWG, 512, 0, stream>>>(xbuf, Wt, bq, bv, qbuf, kbuf, vbuf);

  attn_kernel<<<BDIM * 10 * 3, 256, 0, stream>>>(qbuf, kbuf, vbuf, mask, rbias, out);
}

// Round 18
// 1231.941 us; speedup vs baseline: 1.7992x; 1.1674x over previous
//
#include <hip/hip_runtime.h>
#include <hip/hip_bf16.h>

typedef __bf16 bf16x8 __attribute__((ext_vector_type(8)));
typedef float f32x4 __attribute__((ext_vector_type(4)));
typedef float f32x4u __attribute__((ext_vector_type(4), aligned(4)));

#define NH 12
#define HD 64
#define SEQ 145
#define SP 160
#define DMODEL 768
#define NTOT 2304
#define BDIM 1024
#define RBS 148   // rbias padded row stride (4-aligned float4 rows)

// f32 -> bf16 RNE
__device__ __forceinline__ ushort f2bf(float f) {
  union { float f; uint u; } a; a.f = f;
  uint u = a.u;
  return (ushort)((u + 0x7FFFu + ((u >> 16) & 1u)) >> 16);
}

__device__ __forceinline__ int relidx(int qi, int ki) {
  if (ki == 0) return (qi == 0) ? 531 : 530;
  if (qi == 0) return 529;
  int q = qi - 1, k = ki - 1;
  int qh = q / 12, qw = q - qh * 12;
  int kh = k / 12, kw = k - kh * 12;
  return (qh - kh + 11) * 23 + (qw - kw + 11);
}

// async global->LDS, 16B per lane; lds dest = wave-uniform base + lane*16
__device__ __forceinline__ void gload_lds16(const ushort* g, ushort* l) {
  __builtin_amdgcn_global_load_lds(
      (const __attribute__((address_space(1))) void*)g,
      (__attribute__((address_space(3))) void*)l, 16, 0, 0);
}

#define VMCNT(n) do { asm volatile("s_waitcnt vmcnt(" #n ")" ::: "memory"); \
                      __builtin_amdgcn_sched_barrier(0); } while (0)

// ---------------- prep: Wt[n][k] = W_sel[k][n%768] as bf16 ----------------
__global__ void prep_w(const float* __restrict__ Wq, const float* __restrict__ Wk,
                       const float* __restrict__ Wv, ushort* __restrict__ Wt) {
  int i = blockIdx.x * 256 + threadIdx.x;
  if (i >= NTOT * DMODEL) return;
  int n = i / DMODEL, k = i - n * DMODEL;
  const float* W = (n < DMODEL) ? Wq : (n < 2 * DMODEL ? Wk : Wv);
  int c = n % DMODEL;
  Wt[i] = f2bf(W[k * DMODEL + c]);
}

// ---------------- x f32 -> bf16 (into d_out scratch) ----------------
__global__ void x2bf(const float* __restrict__ x, ushort* __restrict__ xb) {
  const size_t total = (size_t)BDIM * SEQ * DMODEL;
  size_t i = ((size_t)blockIdx.x * 256 + threadIdx.x) * 8;
  if (i >= total) return;
  float4 a = *reinterpret_cast<const float4*>(x + i);
  float4 c = *reinterpret_cast<const float4*>(x + i + 4);
  uint4 o;
  o.x = (uint)f2bf(a.x) | ((uint)f2bf(a.y) << 16);
  o.y = (uint)f2bf(a.z) | ((uint)f2bf(a.w) << 16);
  o.z = (uint)f2bf(c.x) | ((uint)f2bf(c.y) << 16);
  o.w = (uint)f2bf(c.z) | ((uint)f2bf(c.w) << 16);
  *reinterpret_cast<uint4*>(xb + i) = o;
}

// ---------------- zero pad region of transposed V buffer ----------------
__global__ void zero_vpad(ushort* __restrict__ vbuf) {
  int i = blockIdx.x * 256 + threadIdx.x;
  const int total = BDIM * NH * HD * (SP - SEQ);
  if (i >= total) return;
  int s = SEQ + i % (SP - SEQ);
  int row = i / (SP - SEQ);
  vbuf[(size_t)row * SP + s] = 0;
}

// ---------------- rel bias table: rbias[h][qi][ki], row stride RBS ----------------
__global__ void rel_prep(const float* __restrict__ tbl, float* __restrict__ rbias) {
  int i = blockIdx.x * 256 + threadIdx.x;
  if (i >= NH * SEQ * RBS) return;
  int h = i / (SEQ * RBS);
  int rem = i - h * SEQ * RBS;
  int qi = rem / RBS, ki = rem - qi * RBS;
  rbias[i] = (ki < SEQ) ? tbl[relidx(qi, ki) * NH + h] : 0.f;
}

// ---------------- fused QKV GEMM: [148480,768] x [768,2304] ----------------
// 128x256 tile, 8 waves (2x4), per-wave 64x64; BK=32 TRIPLE-buffered (72 KB
// LDS -> 2 blocks/CU). Stage t+2 while computing t, vmcnt(3). V-epilogue
// transposes through per-wave LDS so global stores are coalesced 16B.
#define GNT 9
#define GNWG 10440   // 1160 * 9
#define NKT 24       // 768 / 32

__global__ __launch_bounds__(512, 4)
void qkv_gemm(const ushort* __restrict__ xb, const ushort* __restrict__ Wt,
              const float* __restrict__ bq, const float* __restrict__ bv,
              ushort* __restrict__ qbuf, ushort* __restrict__ kbuf,
              ushort* __restrict__ vbuf) {
  // A[3][4096] at 0; B[3][8192] at 12288 (ushort indices). 72 KB total.
  // After the K-loop this array is reused as 8 x 4608-ushort per-wave
  // transpose scratch (8*9216 B = 73728 B, exact fit).
  __shared__ __align__(16) ushort lds[36864];

  int bid = blockIdx.x;
  int logical = (bid & 7) * 1305 + (bid >> 3);   // 10440 % 8 == 0, bijective
  int mt = logical / GNT, nt = logical - (logical / GNT) * GNT;
  int m0 = mt * 128, n0 = nt * 256;

  int tid = threadIdx.x;
  int l = tid & 63, w = tid >> 6;
  int wm = w >> 2, wn = w & 3;          // 2 x 4 wave grid
  int l15 = l & 15, l4 = l >> 4;
  int rslot = l4 ^ ((l15 >> 1) & 3);    // read-side swizzle (BK=32: 4 slots)

  // staging: thread t -> row (t>>2), stored slot (t&3); src chunk inverse-swz
  int srow = tid >> 2;                  // 0..127
  int schunk = (tid & 3) ^ ((tid >> 3) & 3);
  const ushort* aSrc  = xb + (size_t)(m0 + srow) * DMODEL + schunk * 8;
  const ushort* bSrc0 = Wt + (size_t)(n0 + srow) * DMODEL + schunk * 8;
  const ushort* bSrc1 = Wt + (size_t)(n0 + 128 + srow) * DMODEL + schunk * 8;
  int wdst = w << 9;   // w*512 ushorts (wave-contiguous dest)

#define STAGE(db, kof) do { \
    gload_lds16(aSrc  + (kof), &lds[(db) * 4096 + wdst]); \
    gload_lds16(bSrc0 + (kof), &lds[12288 + (db) * 8192 + wdst]); \
    gload_lds16(bSrc1 + (kof), &lds[12288 + (db) * 8192 + 4096 + wdst]); \
  } while (0)

  f32x4 acc[4][4];
  #pragma unroll
  for (int m = 0; m < 4; m++)
    #pragma unroll
    for (int n = 0; n < 4; n++)
      #pragma unroll
      for (int e = 0; e < 4; e++) acc[m][n][e] = 0.f;

  bf16x8 af[4], bfv[4];

#define LOADFRAG(db) do { \
    int ab_ = (db) * 4096, bb_ = 12288 + (db) * 8192; \
    _Pragma("unroll") \
    for (int i_ = 0; i_ < 4; i_++) \
      af[i_] = *reinterpret_cast<const bf16x8*>( \
          &lds[ab_ + ((wm * 64 + i_ * 16 + l15) << 5) + rslot * 8]); \
    _Pragma("unroll") \
    for (int n_ = 0; n_ < 4; n_++) \
      bfv[n_] = *reinterpret_cast<const bf16x8*>( \
          &lds[bb_ + ((wn * 64 + n_ * 16 + l15) << 5) + rslot * 8]); \
  } while (0)
#define MFMA16() do { \
    __builtin_amdgcn_s_setprio(1); \
    _Pragma("unroll") \
    for (int i_ = 0; i_ < 4; i_++) \
      _Pragma("unroll") \
      for (int n_ = 0; n_ < 4; n_++) \
        acc[i_][n_] = __builtin_amdgcn_mfma_f32_16x16x32_bf16( \
            af[i_], bfv[n_], acc[i_][n_], 0, 0, 0); \
    __builtin_amdgcn_s_setprio(0); \
  } while (0)

  // prologue: stage tiles 0 and 1; wait tile 0 only (tile 1 stays in flight)
  STAGE(0, 0);
  STAGE(1, 32);
  VMCNT(3);
  __builtin_amdgcn_s_barrier();

  #pragma unroll
  for (int t = 0; t < NKT; ++t) {
    int cur = t % 3, nx2 = (t + 2) % 3;
    if (t + 2 < NKT) STAGE(nx2, (t + 2) * 32);   // deep prefetch (tile t+2)
    LOADFRAG(cur);                                // published at t-1's barrier
    MFMA16();                                     // lgkmcnt auto-inserted
    if (t < NKT - 1) {
      if (t + 2 < NKT) { VMCNT(3); }              // retire t+1; t+2 in flight
      else             { VMCNT(0); }              // tail: retire final tile
      __builtin_amdgcn_s_barrier();               // publish t+1
    }
  }

  // ---- epilogue ----
  int which = n0 / DMODEL;
  int h_[4], dh_[4];
  float bias_[4];
  #pragma unroll
  for (int nn = 0; nn < 4; nn++) {
    int col = n0 + wn * 64 + nn * 16 + l15;
    int hcol = col - which * DMODEL;
    h_[nn] = hcol >> 6; dh_[nn] = hcol & 63;
    bias_[nn] = (which == 0) ? bq[hcol] : (which == 2 ? bv[hcol] : 0.f);
  }

  if (which != 2) {
    // q / k: coalesced-enough direct stores (dh consecutive per l15)
    #pragma unroll
    for (int i = 0; i < 4; i++) {
      #pragma unroll
      for (int r = 0; r < 4; r++) {
        int row = m0 + wm * 64 + i * 16 + (l4 << 2) + r;
        int b = row / SEQ;
        int s = row - b * SEQ;
        #pragma unroll
        for (int nn = 0; nn < 4; nn++) {
          float v = acc[i][nn][r] + bias_[nn];
          size_t bh = (size_t)b * NH + h_[nn];
          if (which == 0) {
            v *= 0.125f;  // fold 1/sqrt(64)
            qbuf[(bh * SEQ + s) * HD + dh_[nn]] = f2bf(v);
          } else {
            kbuf[(bh * SEQ + s) * HD + dh_[nn]] = f2bf(v);
          }
        }
      }
    }
  } else {
    // V: transpose through per-wave LDS, then coalesced 16B stores along s.
    __syncthreads();                 // all K-loop ds_reads complete; LDS free
    ushort* T = &lds[w * 4608];      // [64 cols(dh)][72 rows(s)+pad] per wave
    #pragma unroll
    for (int i = 0; i < 4; i++) {
      #pragma unroll
      for (int nn = 0; nn < 4; nn++) {
        int cl = nn * 16 + l15;          // col_local = dh index
        int rl = i * 16 + (l4 << 2);     // row_local base (4 rows)
        ushort4 pk;
        pk.x = f2bf(acc[i][nn][0] + bias_[nn]);
        pk.y = f2bf(acc[i][nn][1] + bias_[nn]);
        pk.z = f2bf(acc[i][nn][2] + bias_[nn]);
        pk.w = f2bf(acc[i][nn][3] + bias_[nn]);
        *reinterpret_cast<ushort4*>(&T[cl * 72 + rl]) = pk;   // ds_write_b64
      }
    }
    asm volatile("s_waitcnt lgkmcnt(0)" ::: "memory");
    __builtin_amdgcn_sched_barrier(0);
    int hU = ((n0 - 2 * DMODEL) >> 6) + wn;    // uniform head for this wave
    int rowbase = m0 + wm * 64;
    #pragma unroll
    for (int c = 0; c < 8; c++) {
      uint4 vv = *reinterpret_cast<const uint4*>(&T[l * 72 + c * 8]);
      int R = rowbase + c * 8;
      int b0 = R / SEQ;
      int b7 = (R + 7) / SEQ;
      if (b0 == b7) {
        int s0 = R - b0 * SEQ;
        size_t addr = (((size_t)b0 * NH + hU) * HD + l) * SP + s0;
        *reinterpret_cast<uint4*>(vbuf + addr) = vv;   // 16B contiguous in s
      } else {
        const ushort* pv = reinterpret_cast<const ushort*>(&vv);
        #pragma unroll
        for (int e = 0; e < 8; e++) {
          int row = R + e;
          int bb = row / SEQ, ss = row - bb * SEQ;
          vbuf[(((size_t)bb * NH + hU) * HD + l) * SP + ss] = pv[e];
        }
      }
    }
  }
#undef STAGE
#undef LOADFRAG
#undef MFMA16
}

// ---------------- fused windowed attention (K/V resident in registers) ------
// block = (b, head-group of 4); wave = head. Each wave loads its head's FULL
// K and V into 160 VGPRs ONCE (fragments are strip-invariant in swapped-QK
// form), then iterates all 10 strips reusing them: per-strip loads drop to
// Q+mask+rbias only, and K/V HBM re-reads drop ~10x. launch_bounds(256,2):
// VGPR cap 256 >= ~235 needed, no spill. XCD b-affinity: b % 8 == xcd.
#define AH 4
__global__ __launch_bounds__(256, 2)
void attn_kernel(const ushort* __restrict__ qbuf, const ushort* __restrict__ kbuf,
                 const ushort* __restrict__ vbuf, const float* __restrict__ mask,
                 const float* __restrict__ rbias, float* __restrict__ out) {
  __shared__ __align__(16) ushort plds[AH][16][SP + 8];  // 21 KB

  int id = blockIdx.x;
  int xcd = id & 7;
  int j = id >> 3;                 // 0..383
  int b = xcd + 8 * (j / 3);       // b % 8 == xcd
  int hg = j % 3;

  int tid = threadIdx.x;
  int lane = tid & 63, w = tid >> 6;
  int h = hg * AH + w;             // wave -> head
  int l15 = lane & 15, l4 = lane >> 4;
  int bh = b * NH + h;

  const ushort* qp = qbuf + (size_t)bh * SEQ * HD;
  const ushort* kp = kbuf + (size_t)bh * SEQ * HD;
  const ushort* vp = vbuf + (size_t)bh * HD * SP;
  const float* mbase = mask + (size_t)b * SEQ * SEQ;
  const float* rbase = rbias + (size_t)h * SEQ * RBS;

  // ---- load the head's FULL K into registers (strip-invariant) ----
  uint4 kfa[10], kfb[10];
  #pragma unroll
  for (int ct = 0; ct < 5; ct++) {
    int krow = ct * 16 + l15;            // <= 79 < SEQ
    kfa[2 * ct]     = *reinterpret_cast<const uint4*>(kp + krow * HD + l4 * 8);
    kfa[2 * ct + 1] = *reinterpret_cast<const uint4*>(kp + krow * HD + 32 + l4 * 8);
  }
  #pragma unroll
  for (int ct = 5; ct < 10; ct++) {
    int krow = ct * 16 + l15;
    if (krow >= SEQ) krow = 0;           // clamp: masked via -3e38 init
    kfb[2 * (ct - 5)]     = *reinterpret_cast<const uint4*>(kp + krow * HD + l4 * 8);
    kfb[2 * (ct - 5) + 1] = *reinterpret_cast<const uint4*>(kp + krow * HD + 32 + l4 * 8);
  }
  // ---- load the head's FULL V^T into registers (strip-invariant) ----
  uint4 vba[10], vbb[10];
  #pragma unroll
  for (int t = 0; t < 10; t++) {
    int ntl = t / 5, ks = t % 5;
    vba[t] = *reinterpret_cast<const uint4*>(
        vp + (ntl * 16 + l15) * SP + ks * 32 + l4 * 8);
  }
  #pragma unroll
  for (int t = 0; t < 10; t++) {
    int ntl = 2 + t / 5, ks = t % 5;
    vbb[t] = *reinterpret_cast<const uint4*>(
        vp + (ntl * 16 + l15) * SP + ks * 32 + l4 * 8);
  }

  // ---- strip loop: K/V stay resident; only Q/mask/rbias stream ----
  #pragma unroll 1
  for (int strip = 0; strip < 10; strip++) {
    int r0 = strip * 16;
    int qi = r0 + l15;
    int qc = (qi < SEQ) ? qi : (SEQ - 1);
    bool qok = (qi < SEQ);
    const float* mrow = mbase + (size_t)qc * SEQ;
    const float* rp = rbase + (size_t)qc * RBS;

    // Q fragment (B-operand, col = qi)
    bf16x8 qf0, qf1;
    if (qok) {
      qf0 = *reinterpret_cast<const bf16x8*>(qp + qi * HD + l4 * 8);
      qf1 = *reinterpret_cast<const bf16x8*>(qp + qi * HD + 32 + l4 * 8);
    } else {
      uint4 z = make_uint4(0, 0, 0, 0);
      qf0 = *reinterpret_cast<bf16x8*>(&z);
      qf1 = *reinterpret_cast<bf16x8*>(&z);
    }

    // init accumulators with mask + rel bias (-3e38 where masked)
    f32x4 sc[10];
    #pragma unroll
    for (int ct = 0; ct < 9; ct++) {
      int kb = ct * 16 + l4 * 4;
      f32x4u rb = *reinterpret_cast<const f32x4u*>(rp + kb);
      f32x4u mk = *reinterpret_cast<const f32x4u*>(mrow + kb);
      #pragma unroll
      for (int r = 0; r < 4; r++)
        sc[ct][r] = qok ? (mk[r] + rb[r]) : -3e38f;
    }
    {
      float iv = (l4 == 0 && qok) ? (mrow[144] + rp[144]) : -3e38f;
      sc[9][0] = iv; sc[9][1] = -3e38f; sc[9][2] = -3e38f; sc[9][3] = -3e38f;
    }

    // QK^T from resident K registers
    #pragma unroll
    for (int ct = 0; ct < 5; ct++) {
      sc[ct] = __builtin_amdgcn_mfma_f32_16x16x32_bf16(
          *reinterpret_cast<bf16x8*>(&kfa[2 * ct]), qf0, sc[ct], 0, 0, 0);
      sc[ct] = __builtin_amdgcn_mfma_f32_16x16x32_bf16(
          *reinterpret_cast<bf16x8*>(&kfa[2 * ct + 1]), qf1, sc[ct], 0, 0, 0);
    }
    #pragma unroll
    for (int ct = 5; ct < 10; ct++) {
      sc[ct] = __builtin_amdgcn_mfma_f32_16x16x32_bf16(
          *reinterpret_cast<bf16x8*>(&kfb[2 * (ct - 5)]), qf0, sc[ct], 0, 0, 0);
      sc[ct] = __builtin_amdgcn_mfma_f32_16x16x32_bf16(
          *reinterpret_cast<bf16x8*>(&kfb[2 * (ct - 5) + 1]), qf1, sc[ct], 0, 0, 0);
    }

    // softmax over ki
    float mx = -3e38f;
    #pragma unroll
    for (int ct = 0; ct < 10; ct++)
      #pragma unroll
      for (int r = 0; r < 4; r++) mx = fmaxf(mx, sc[ct][r]);
    mx = fmaxf(mx, __shfl_xor(mx, 16, 64));
    mx = fmaxf(mx, __shfl_xor(mx, 32, 64));
    float sum = 0.f;
    #pragma unroll
    for (int ct = 0; ct < 10; ct++)
      #pragma unroll
      for (int r = 0; r < 4; r++) {
        float p = __expf(sc[ct][r] - mx);
        sc[ct][r] = p;
        sum += p;
      }
    sum += __shfl_xor(sum, 16, 64);
    sum += __shfl_xor(sum, 32, 64);
    float inv = 1.f / sum;

    // P (bf16) to per-wave LDS (C-layout -> A-layout transpose)
    #pragma unroll
    for (int ct = 0; ct < 10; ct++) {
      ushort4 pk;
      pk.x = f2bf(sc[ct][0] * inv);
      pk.y = f2bf(sc[ct][1] * inv);
      pk.z = f2bf(sc[ct][2] * inv);
      pk.w = f2bf(sc[ct][3] * inv);
      *reinterpret_cast<ushort4*>(&plds[w][l15][ct * 16 + l4 * 4]) = pk;
    }

    // PV from resident V registers
    #pragma unroll
    for (int ntl = 0; ntl < 2; ntl++) {
      f32x4 pacc;
      #pragma unroll
      for (int e = 0; e < 4; e++) pacc[e] = 0.f;
      #pragma unroll
      for (int ks = 0; ks < 5; ks++) {
        bf16x8 pa = *reinterpret_cast<const bf16x8*>(
            &plds[w][l15][ks * 32 + l4 * 8]);
        pacc = __builtin_amdgcn_mfma_f32_16x16x32_bf16(
            pa, *reinterpret_cast<bf16x8*>(&vba[ntl * 5 + ks]), pacc, 0, 0, 0);
      }
      #pragma unroll
      for (int r = 0; r < 4; r++) {
        int s = r0 + l4 * 4 + r;
        if (s < SEQ)
          out[((size_t)b * SEQ + s) * DMODEL + h * HD + ntl * 16 + l15] = pacc[r];
      }
    }
    #pragma unroll
    for (int ntl = 2; ntl < 4; ntl++) {
      f32x4 pacc;
      #pragma unroll
      for (int e = 0; e < 4; e++) pacc[e] = 0.f;
      #pragma unroll
      for (int ks = 0; ks < 5; ks++) {
        bf16x8 pa = *reinterpret_cast<const bf16x8*>(
            &plds[w][l15][ks * 32 + l4 * 8]);
        pacc = __builtin_amdgcn_mfma_f32_16x16x32_bf16(
            pa, *reinterpret_cast<bf16x8*>(&vbb[(ntl - 2) * 5 + ks]), pacc, 0, 0, 0);
      }
      #pragma unroll
      for (int r = 0; r < 4; r++) {
        int s = r0 + l4 * 4 + r;
        if (s < SEQ)
          out[((size_t)b * SEQ + s) * DMODEL + h * HD + ntl * 16 + l15] = pacc[r];
      }
    }
  }
}

extern "C" void kernel_launch(void* const* d_in, const int* in_sizes, int n_in,
                              void* d_out, int out_size, void* d_ws, size_t ws_size,
                              hipStream_t stream) {
  const float* x    = (const float*)d_in[0];
  const float* mask = (const float*)d_in[1];
  const float* Wq   = (const float*)d_in[2];
  const float* bq   = (const float*)d_in[3];
  const float* Wk   = (const float*)d_in[4];
  const float* Wv   = (const float*)d_in[5];
  const float* bv   = (const float*)d_in[6];
  const float* tbl  = (const float*)d_in[7];
  float* out = (float*)d_out;

  char* ws = (char*)d_ws;
  ushort* Wt = (ushort*)ws;                         // 3,538,944 B
  size_t off = (size_t)NTOT * DMODEL * 2;
  ushort* qbuf = (ushort*)(ws + off); off += (size_t)BDIM * NH * SEQ * HD * 2;
  ushort* kbuf = (ushort*)(ws + off); off += (size_t)BDIM * NH * SEQ * HD * 2;
  ushort* vbuf = (ushort*)(ws + off); off += (size_t)BDIM * NH * HD * SP * 2;
  float*  rbias = (float*)(ws + off); off += (size_t)NH * SEQ * RBS * 4 + 64;
  // ~713 MB of d_ws

  // bf16 x lives in d_out scratch (456 MB f32 out >= 228 MB bf16 x);
  // attn_kernel later overwrites every element of d_out.
  ushort* xbuf = (ushort*)d_out;

  prep_w<<<(NTOT * DMODEL + 255) / 256, 256, 0, stream>>>(Wq, Wk, Wv, Wt);
  zero_vpad<<<(BDIM * NH * HD * (SP - SEQ) + 255) / 256, 256, 0, stream>>>(vbuf);
  rel_prep<<<(NH * SEQ * RBS + 255) / 256, 256, 0, stream>>>(tbl, rbias);
  {
    size_t total = (size_t)BDIM * SEQ * DMODEL;
    x2bf<<<(int)(total / 8 / 256), 256, 0, stream>>>(x, xbuf);
  }

  qkv_gemm<<<GNWG, 512, 0, stream>>>(xbuf, Wt, bq, bv, qbuf, kbuf, vbuf);

  attn_kernel<<<BDIM * 3, 256, 0, stream>>>(qbuf, kbuf, vbuf, mask, rbias, out);
}